// Round 17
// baseline (989.545 us; speedup 1.0000x reference)
//
#include <hip/hip_runtime.h>
#include <cstdint>
#include <cstddef>

#define B_   64
#define T_   300
#define DIN_ 768
#define D_   300
#define E_   8
#define NTOK (B_*T_)   // 19200
#define TW   10        // t's per attention block (10 waves)
#define SC   32        // KV staging chunk rows (keeps p[TW][4][304]+kv < 64KB)

typedef __attribute__((ext_vector_type(8))) short bf8_t;           // 8 bf16 (4 VGPR)
typedef __attribute__((ext_vector_type(4))) float f4_t;            // 4 fp32 acc

__device__ __forceinline__ unsigned short f2bf(float v) {
  union { float f; unsigned u; } a; a.f = v;
  unsigned r = a.u + 0x7fff + ((a.u >> 16) & 1);   // RNE
  return (unsigned short)(r >> 16);
}
__device__ __forceinline__ float bf2f(unsigned short s) {
  union { float f; unsigned u; } a; a.u = ((unsigned)s) << 16; return a.f;
}
// v ~= p0 + p1 + p2 (24 mantissa bits)
__device__ __forceinline__ void split3(float v, unsigned short& p0,
                                       unsigned short& p1, unsigned short& p2) {
  p0 = f2bf(v);
  float r1 = v - bf2f(p0);
  p1 = f2bf(r1);
  float r2 = r1 - bf2f(p1);
  p2 = f2bf(r2);
}
// v ~= p0 + p1 (17 mantissa bits)
__device__ __forceinline__ void split2(float v, unsigned short& p0,
                                       unsigned short& p1) {
  p0 = f2bf(v);
  p1 = f2bf(v - bf2f(p0));
}

// direct global->LDS 16B DMA (width=16, m97/m151 pattern)
__device__ __forceinline__ void gld16(const unsigned short* g, unsigned short* l) {
  __builtin_amdgcn_global_load_lds(
      (const __attribute__((address_space(1))) unsigned int*)g,
      (__attribute__((address_space(3))) unsigned int*)l, 16, 0, 0);
}

// ---------------------------------------------------------------------------
__global__ void biasproj_kernel(const float* __restrict__ wh_bias,
                                const float* __restrict__ wh_W,
                                float* __restrict__ bp) {
  int o = blockIdx.x * blockDim.x + threadIdx.x;
  if (o >= D_) return;
  float acc = 0.f;
  const float* row = wh_W + (size_t)o * DIN_;
  for (int d = 0; d < DIN_; ++d) acc += wh_bias[d] * row[d];
  bp[o] = -acc;
}

// ---------------------------------------------------------------------------
// split fp32 [rows][K] -> np bf16 planes [rows][Kp], zero-padded cols
// ---------------------------------------------------------------------------
__global__ void split_pad(const float* __restrict__ src, unsigned short* __restrict__ dst,
                          int rows, int K, int Kp, size_t planeStride, int np) {
  int n = rows * Kp;
  for (int i = blockIdx.x * blockDim.x + threadIdx.x; i < n; i += gridDim.x * blockDim.x) {
    int r = i / Kp, c = i % Kp;
    unsigned short p0 = 0, p1 = 0, p2 = 0;
    if (c < K) split3(src[(size_t)r * K + c], p0, p1, p2);
    dst[i] = p0;
    dst[planeStride + i] = p1;
    if (np == 3) dst[2 * planeStride + i] = p2;
  }
}

// ---------------------------------------------------------------------------
// MFMA GEMM, fp32 emulated via NP bf16 planes (NP=3: 6 products; NP=2: 3).
// (r15-proven body: frag-reads -> barrier -> next-stage issue ∥ MFMA -> barrier)
// Staging: B (and A when AFP=0) via global_load_lds width-16 into LINEAR LDS
// [row][32 shorts], chunk-XOR swizzle c_phys = c_log ^ ((row>>1)&3) applied
// on SOURCE address and FRAG-READ address (both-sides rule).
// SWZ=1: bijective XCD-aware block remap (T1, m204 form).
// AFP=1: A fp32 split3-on-stage via ds_write (requires NP=3).
// EPI: 0 = C = acc (+bias)                    [fp32 out]
//      1 = planes(relu(acc+bias)) -> Po       [G1 -> h planes]
//      2 = gsum = g*eo, esum = eo             (eo = acc+bias)
//      3 = gsum += g*eo, esum += eo
//      4 = C = (gsum+g*eo)*(esum+eo)
//      5 = planes(acc+bias) -> Po             [whiten -> xw planes]
//      6 = C = acc+bias AND planes -> Po      [proj -> xa + xa planes]
// Plane epilogues ZERO pads for N <= col < ldPo (NaN*0=NaN downstream else).
// ---------------------------------------------------------------------------
template<int AFP, int EPI, int JN, int WM, int NP, int NPO, int SWZ>
__global__ __launch_bounds__(WM * 64) void mfma_gen(
    const void* __restrict__ Av, size_t aPStride, int ldA,
    const unsigned short* __restrict__ Bg, size_t bPStride,
    const float* __restrict__ bias, float* __restrict__ C,
    unsigned short* __restrict__ Po, size_t poStride, int ldPo,
    float* __restrict__ gsum, float* __restrict__ esum,
    const float* __restrict__ gate,
    int M, int N, int K) {
  constexpr int TILE_M = WM * 32;
  constexpr int BROWS  = JN * 32;
  constexpr int APB    = TILE_M * 64;        // bytes per A plane in LDS
  constexpr int BPB    = BROWS * 64;
  constexpr int AINSTS = NP * APB / 1024;    // gload_lds instrs for A
  constexpr int BINSTS = NP * BPB / 1024;
  static_assert(!AFP || NP == 3, "AFP path writes 3 planes");
  __shared__ unsigned short Ap[NP][TILE_M * 32];
  __shared__ unsigned short Bp[NP][BROWS * 32];
  const int tid = threadIdx.x;
  // block-id -> tile mapping (optionally XCD-swizzled, bijective for any nwg)
  int bxv = blockIdx.x, byv = blockIdx.y;
  if constexpr (SWZ) {
    const int nx  = gridDim.x;
    const int nwg = nx * gridDim.y;
    const int id  = byv * nx + bxv;
    const int xcd = id & 7, idx = id >> 3;
    const int q = nwg >> 3, r = nwg & 7;
    const int nid = (xcd < r) ? (xcd * (q + 1) + idx)
                              : (r * (q + 1) + (xcd - r) * q + idx);
    bxv = nid % nx;
    byv = nid / nx;
  }
  const int bm = byv * TILE_M, bn = bxv * BROWS;
  const int widx = tid >> 6;
  const int wr = (widx >> 1) * 64;           // 0 when WM=2
  const int wc = (widx & 1) * (JN * 16);
  const int lane = tid & 63;
  const int lr = lane & 15;
  const int kg = lane >> 4;
  const int sw = (lr >> 1) & 3;              // read-side chunk swizzle
  const int Kp = (K + 31) & ~31;
  // AFP staging map
  const int arow = tid >> 1, ahalf = (tid & 1) * 16;
  const int asw = (arow >> 1) & 3;

  auto stageB = [&](int k0) {
    for (int q = widx; q < BINSTS; q += WM) {
      const int f   = q * 1024 + lane * 16;
      const int pp  = f / BPB;
      const int rem = f % BPB;
      const int row = rem >> 6;
      const int cl  = ((rem >> 4) & 3) ^ ((row >> 1) & 3);
      int brow = bn + row; if (brow >= N) brow = N - 1;
      gld16(Bg + (size_t)pp * bPStride + (size_t)brow * Kp + k0 + cl * 8,
            (unsigned short*)Bp + q * 512);
    }
  };
  auto stageA = [&](int k0) {
    if constexpr (AFP) {
      const float* Arow = (const float*)Av + (size_t)(bm + arow) * ldA + k0 + ahalf;
      #pragma unroll
      for (int u = 0; u < 4; ++u) {
        float4 qv = *(const float4*)&Arow[u * 4];
        float vv[4] = {qv.x, qv.y, qv.z, qv.w};
        unsigned short s0[4], s1[4], s2[4];
        #pragma unroll
        for (int w = 0; w < 4; ++w) split3(vv[w], s0[w], s1[w], s2[w]);
        const int k  = ahalf + u * 4;
        const int so = arow * 32 + (((k >> 3) ^ asw) << 3) + (k & 7);
        *(unsigned*)&Ap[0][so]     = (unsigned)s0[0] | ((unsigned)s0[1] << 16);
        *(unsigned*)&Ap[0][so + 2] = (unsigned)s0[2] | ((unsigned)s0[3] << 16);
        *(unsigned*)&Ap[1][so]     = (unsigned)s1[0] | ((unsigned)s1[1] << 16);
        *(unsigned*)&Ap[1][so + 2] = (unsigned)s1[2] | ((unsigned)s1[3] << 16);
        *(unsigned*)&Ap[2][so]     = (unsigned)s2[0] | ((unsigned)s2[1] << 16);
        *(unsigned*)&Ap[2][so + 2] = (unsigned)s2[2] | ((unsigned)s2[3] << 16);
      }
    } else {
      for (int q = widx; q < AINSTS; q += WM) {
        const int f   = q * 1024 + lane * 16;
        const int pp  = f / APB;
        const int rem = f % APB;
        const int row = rem >> 6;
        const int cl  = ((rem >> 4) & 3) ^ ((row >> 1) & 3);
        gld16((const unsigned short*)Av + (size_t)pp * aPStride +
                  (size_t)(bm + row) * Kp + k0 + cl * 8,
              (unsigned short*)Ap + q * 512);
      }
    }
  };

  f4_t acc[4][JN];
  #pragma unroll
  for (int i = 0; i < 4; ++i)
    #pragma unroll
    for (int j = 0; j < JN; ++j) acc[i][j] = (f4_t){0.f, 0.f, 0.f, 0.f};

  stageB(0); stageA(0);
  __syncthreads();
  for (int k0 = 0; k0 < Kp; k0 += 32) {
    // ---- frag reads (swizzled) ----
    bf8_t a[4][NP], b[JN][NP];
    #pragma unroll
    for (int i = 0; i < 4; ++i)
      #pragma unroll
      for (int p = 0; p < NP; ++p)
        a[i][p] = *(const bf8_t*)&Ap[p][(wr + i * 16 + lr) * 32 + ((kg ^ sw) << 3)];
    #pragma unroll
    for (int j = 0; j < JN; ++j)
      #pragma unroll
      for (int p = 0; p < NP; ++p)
        b[j][p] = *(const bf8_t*)&Bp[p][(wc + j * 16 + lr) * 32 + ((kg ^ sw) << 3)];
    __syncthreads();   // all waves done reading -> LDS reusable
    if (k0 + 32 < Kp) { stageB(k0 + 32); stageA(k0 + 32); }   // fly under MFMA
    #pragma unroll
    for (int i = 0; i < 4; ++i)
      #pragma unroll
      for (int j = 0; j < JN; ++j) {
        f4_t c = acc[i][j];
        if constexpr (NP == 3) {
          c = __builtin_amdgcn_mfma_f32_16x16x32_bf16(a[i][2], b[j][0], c, 0, 0, 0);
          c = __builtin_amdgcn_mfma_f32_16x16x32_bf16(a[i][1], b[j][1], c, 0, 0, 0);
          c = __builtin_amdgcn_mfma_f32_16x16x32_bf16(a[i][0], b[j][2], c, 0, 0, 0);
          c = __builtin_amdgcn_mfma_f32_16x16x32_bf16(a[i][1], b[j][0], c, 0, 0, 0);
          c = __builtin_amdgcn_mfma_f32_16x16x32_bf16(a[i][0], b[j][1], c, 0, 0, 0);
          c = __builtin_amdgcn_mfma_f32_16x16x32_bf16(a[i][0], b[j][0], c, 0, 0, 0);
        } else {
          c = __builtin_amdgcn_mfma_f32_16x16x32_bf16(a[i][1], b[j][0], c, 0, 0, 0);
          c = __builtin_amdgcn_mfma_f32_16x16x32_bf16(a[i][0], b[j][1], c, 0, 0, 0);
          c = __builtin_amdgcn_mfma_f32_16x16x32_bf16(a[i][0], b[j][0], c, 0, 0, 0);
        }
        acc[i][j] = c;
      }
    __syncthreads();   // next stage drained (vmcnt+lgkm)
  }
  // ---- epilogue ----
  #pragma unroll
  for (int i = 0; i < 4; ++i) {
    #pragma unroll
    for (int r = 0; r < 4; ++r) {
      const int row = bm + wr + i * 16 + kg * 4 + r;
      float g = 0.f;
      if constexpr (EPI >= 2 && EPI <= 4) g = gate[(size_t)row * E_];
      #pragma unroll
      for (int j = 0; j < JN; ++j) {
        const int col = bn + wc + j * 16 + lr;
        float v = acc[i][j][r];
        if constexpr (EPI == 0) {
          if (col < N) {
            if (bias) v += bias[col];
            C[(size_t)row * N + col] = v;
          }
        } else if constexpr (EPI == 1 || EPI == 5 || EPI == 6) {
          if (col < ldPo) {
            unsigned short p0 = 0, p1 = 0, p2 = 0;
            if (col < N) {
              v += bias[col];
              if constexpr (EPI == 1) v = fmaxf(v, 0.f);
              if constexpr (EPI == 6) C[(size_t)row * N + col] = v;
              if constexpr (NPO == 3) split3(v, p0, p1, p2);
              else                    split2(v, p0, p1);
            }
            size_t o = (size_t)row * ldPo + col;
            Po[o] = p0;
            Po[poStride + o] = p1;
            if constexpr (NPO == 3) Po[2 * poStride + o] = p2;
          }
        } else {
          if (col < N) {
            float eo = v + bias[col];
            size_t idx = (size_t)row * N + col;
            if constexpr (EPI == 2) {
              gsum[idx] = g * eo;
              esum[idx] = eo;
            } else if constexpr (EPI == 3) {
              gsum[idx] += g * eo;
              esum[idx] += eo;
            } else {
              float gs = gsum[idx] + g * eo;
              float es = esum[idx] + eo;
              C[idx] = gs * es;
            }
          }
        }
      }
    }
  }
}

// ---------------------------------------------------------------------------
// Attention, KV-shared form (r16 bugfix: per-HEAD score rows p[TW][4][304]).
// One block = (batch b, 10 consecutive t's). 10 waves x 64 thr; wave w owns
// t = tch*10+w; 16 lanes per head. K (then V) staged in 32-row LDS chunks
// once per block; all 10 waves consume from LDS (~10x less L2 traffic).
// Accumulation order identical to round-11 (chunk starts multiples of 4, same
// per-lane s assignment, same o0..o3 striding) -> bit-identical output.
// ---------------------------------------------------------------------------
__global__ __launch_bounds__(64 * TW) void attn_kernel(
    const float* __restrict__ qkv, float* __restrict__ attout) {
  const int nch_blk = T_ / TW;               // 30
  const int b   = blockIdx.x / nch_blk;
  const int tch = blockIdx.x % nch_blk;
  const int w    = threadIdx.x >> 6;
  const int lane = threadIdx.x & 63;
  const int h = lane >> 4, li = lane & 15;
  const int t    = tch * TW + w;
  const int tmax = tch * TW + TW - 1;
  __shared__ float kv[SC][68];               // K chunk, then reused for V
  __shared__ float p[TW][4][304];            // per-(wave, head) score rows
  const float scale = rsqrtf((float)D_);
  const float* base = qkv + (size_t)b * T_ * 192;
  const float* qrow = base + (size_t)t * 192 + h * 16;
  const float4 q0 = *(const float4*)(qrow);
  const float4 q1 = *(const float4*)(qrow + 4);
  const float4 q2 = *(const float4*)(qrow + 8);
  const float4 q3 = *(const float4*)(qrow + 12);
  const int nch = tmax / SC + 1;             // chunks covering s in [0, tmax]

  // ---- pass 1: K chunks -> scores in p[w][h][*], track per-lane max ----
  float mmax = -1e30f;
  for (int c = 0; c < nch; ++c) {
    const int s0 = c * SC;
    __syncthreads();                          // prior chunk fully consumed
    for (int i = threadIdx.x; i < SC * 16; i += 64 * TW) {
      const int r = i >> 4, c4 = (i & 15) * 4;
      int sr = s0 + r; if (sr > T_ - 1) sr = T_ - 1;   // clamped rows unused
      *(float4*)&kv[r][c4] = *(const float4*)&base[(size_t)sr * 192 + 64 + c4];
    }
    __syncthreads();
    const int send = (s0 + SC - 1 < t) ? s0 + SC - 1 : t;
    for (int s = s0 + li; s <= send; s += 16) {
      const float* kr = &kv[s - s0][h * 16];
      float4 k0 = *(const float4*)(kr);
      float4 k1 = *(const float4*)(kr + 4);
      float4 k2 = *(const float4*)(kr + 8);
      float4 k3 = *(const float4*)(kr + 12);
      float acc = q0.x * k0.x + q0.y * k0.y + q0.z * k0.z + q0.w * k0.w;
      acc += q1.x * k1.x + q1.y * k1.y + q1.z * k1.z + q1.w * k1.w;
      acc += q2.x * k2.x + q2.y * k2.y + q2.z * k2.z + q2.w * k2.w;
      acc += q3.x * k3.x + q3.y * k3.y + q3.z * k3.z + q3.w * k3.w;
      acc *= scale;
      p[w][h][s] = acc;
      mmax = fmaxf(mmax, acc);
    }
  }
  // ---- softmax (own (w,h) rows; 16-lane reduction as r11) ----
  #pragma unroll
  for (int m = 8; m >= 1; m >>= 1) mmax = fmaxf(mmax, __shfl_xor(mmax, m, 16));
  float lsum = 0.f;
  for (int s = li; s <= t; s += 16) {
    float e = __expf(p[w][h][s] - mmax);
    p[w][h][s] = e;
    lsum += e;
  }
  #pragma unroll
  for (int m = 8; m >= 1; m >>= 1) lsum += __shfl_xor(lsum, m, 16);
  const float inv = 1.0f / lsum;

  // ---- pass 2: V chunks -> PV accumulate (r11 order preserved) ----
  float o0 = 0.f, o1 = 0.f, o2 = 0.f, o3 = 0.f;
  for (int c = 0; c < nch; ++c) {
    const int s0 = c * SC;
    __syncthreads();                          // K/prev-V reads done
    for (int i = threadIdx.x; i < SC * 16; i += 64 * TW) {
      const int r = i >> 4, c4 = (i & 15) * 4;
      int sr = s0 + r; if (sr > T_ - 1) sr = T_ - 1;
      *(float4*)&kv[r][c4] = *(const float4*)&base[(size_t)sr * 192 + 128 + c4];
    }
    __syncthreads();
    const int send = (s0 + SC - 1 < t) ? s0 + SC - 1 : t;
    const int col = h * 16 + li;
    int s = s0;
    for (; s + 3 <= send; s += 4) {
      float4 pw = *(const float4*)&p[w][h][s];
      o0 += pw.x * kv[s - s0][col];
      o1 += pw.y * kv[s + 1 - s0][col];
      o2 += pw.z * kv[s + 2 - s0][col];
      o3 += pw.w * kv[s + 3 - s0][col];
    }
    for (; s <= send; ++s) o0 += p[w][h][s] * kv[s - s0][col];
  }
  attout[((size_t)b * T_ + t) * 192 + lane] = ((o0 + o1) + (o2 + o3)) * inv;
}

// ---------------------------------------------------------------------------
__global__ void logits_kernel(const float* __restrict__ xa,
                              const float* __restrict__ w_gate,
                              float* __restrict__ logits) {
  int idx = blockIdx.x * blockDim.x + threadIdx.x;
  if (idx >= NTOK * E_) return;
  int n = idx >> 3, e = idx & 7;
  const float* xr = xa + (size_t)n * D_;
  float acc = 0.f;
  for (int d = 0; d < D_; ++d) acc += xr[d] * w_gate[(size_t)d * E_ + e];
  logits[idx] = acc;
}

// ---------------------------------------------------------------------------
__global__ void gate_kernel(const float* __restrict__ logits,
                            float* __restrict__ gprob) {
  int n = blockIdx.x * blockDim.x + threadIdx.x;
  if (n >= NTOK) return;
  float l[E_];
  #pragma unroll
  for (int e = 0; e < E_; ++e) l[e] = logits[(size_t)n * E_ + e];
  bool sel[E_] = {false, false, false, false, false, false, false, false};
  for (int kk = 0; kk < E_ / 2; ++kk) {
    int bi = -1; float bv = -1e38f;
    #pragma unroll
    for (int e = 0; e < E_; ++e)
      if (!sel[e] && l[e] > bv) { bv = l[e]; bi = e; }
    sel[bi] = true;
  }
  float mx = -1e38f;
  #pragma unroll
  for (int e = 0; e < E_; ++e) if (sel[e]) mx = fmaxf(mx, l[e]);
  float s = 0.f, pp[E_];
  #pragma unroll
  for (int e = 0; e < E_; ++e) {
    pp[e] = sel[e] ? __expf(l[e] - mx) : 0.f;
    s += pp[e];
  }
  float inv = 1.0f / s;
  #pragma unroll
  for (int e = 0; e < E_; ++e) gprob[(size_t)n * E_ + e] = pp[e] * inv;
}

// ---------------------------------------------------------------------------
extern "C" void kernel_launch(void* const* d_in, const int* in_sizes, int n_in,
                              void* d_out, int out_size, void* d_ws, size_t ws_size,
                              hipStream_t stream) {
  const float* x       = (const float*)d_in[0];
  const float* wh_bias = (const float*)d_in[1];
  const float* wh_W    = (const float*)d_in[2];
  const float* Wq      = (const float*)d_in[3];
  const float* Wk      = (const float*)d_in[4];
  const float* Wv      = (const float*)d_in[5];
  const float* proj_W  = (const float*)d_in[6];
  const float* proj_b  = (const float*)d_in[7];
  const float* exp_W1  = (const float*)d_in[8];
  const float* exp_b1  = (const float*)d_in[9];
  const float* exp_W2  = (const float*)d_in[10];
  const float* exp_b2  = (const float*)d_in[11];
  const float* w_gate  = (const float*)d_in[12];
  (void)in_sizes; (void)n_in; (void)out_size;

  char* ws = (char*)d_ws;
  size_t off = 0;
  auto alloc = [&](size_t bytes) {
    void* p = ws + off; off = (off + bytes + 255) & ~(size_t)255; return p;
  };
  typedef unsigned short us;
  float* bp    = (float*)alloc(300 * 4);
  us* whp      = (us*)alloc((size_t)3 * 300 * 768 * 2);          // 3-plane, Kp=768
  us* qkvp     = (us*)alloc((size_t)2 * 192 * 320 * 2);          // 2-plane, Kp=320
  us* projp    = (us*)alloc((size_t)3 * 300 * 64 * 2);           // 3-plane, Kp=64
  us* w1p      = (us*)alloc((size_t)2 * 4800 * 320 * 2);         // 2-plane, Kp=320
  us* w2p      = (us*)alloc(((size_t)2 * 2400 * 608 + 64 * 608) * 2);  // 2-plane +guard
  float* gprob = (float*)alloc((size_t)NTOK * E_ * 4);
  us* xwreg    = (us*)alloc((size_t)2 * NTOK * 320 * 2);   // xw 2-plane / xa fp32 / h (fb)
  float* qkvb  = (float*)alloc((size_t)NTOK * 192 * 4);    // qkv+att; esum (fallback)
  us* xap      = (us*)alloc((size_t)2 * NTOK * 320 * 2);   // xa 2-plane
  // base total ~78 MB. gsum always lives in d_out.

  float* xa = (float*)xwreg;         // [NTOK][300] fp32; dead after gating

  // region plan:
  //  preX: one region of 88.5MB serves x 3-planes (whiten) THEN hpl+esum
  //  else: dedicated hpl+esum (70MB) if it fits; else r11 aliases (CH=9600)
  const size_t xp3Bytes  = (size_t)3 * NTOK * DIN_ * 2;  // 88.5 MB
  const size_t hplBytes  = (size_t)2 * NTOK * 608 * 2;   // 46.7 MB
  const size_t esumBytes = (size_t)NTOK * 300 * 4;       // 23.0 MB
  const size_t hplAl = (hplBytes + 255) & ~(size_t)255;
  int CHe;
  us* hpl;
  float* esum;
  us* xp3 = nullptr;
  bool preX = false;
  if (off + xp3Bytes <= ws_size) {
    char* region = ws + off;
    off += (xp3Bytes + 255) & ~(size_t)255;
    xp3  = (us*)region;                       // whiten phase
    hpl  = (us*)region;                       // expert phase (xp3 dead)
    esum = (float*)(region + hplAl);
    CHe  = NTOK;
    preX = true;
  } else if (off + hplBytes + esumBytes <= ws_size) {
    hpl  = (us*)alloc(hplBytes);
    esum = (float*)alloc(esumBytes);
    CHe  = NTOK;
  } else {
    hpl  = xwreg;                    // 23.3MB <= 24.58MB
    esum = qkvb;                     // 11.5MB <= 14.75MB
    CHe  = 9600;
  }

  // --- weight pre-split ---
  biasproj_kernel<<<2, 256, 0, stream>>>(wh_bias, wh_W, bp);
  auto SP = [&](const float* s, us* dbase, int rows, int K, int Kp, size_t pstr, int np) {
    int n = rows * Kp;
    int g = (n + 255) / 256; if (g > 4096) g = 4096;
    split_pad<<<g, 256, 0, stream>>>(s, dbase, rows, K, Kp, pstr, np);
  };
  SP(wh_W,   whp,              300,  768, 768, (size_t)300 * 768, 3);
  SP(Wq,     qkvp,             64,   300, 320, (size_t)192 * 320, 2);
  SP(Wk,     qkvp + 64 * 320,  64,   300, 320, (size_t)192 * 320, 2);
  SP(Wv,     qkvp + 128 * 320, 64,   300, 320, (size_t)192 * 320, 2);
  SP(proj_W, projp,            300,  64,  64,  (size_t)300 * 64, 3);
  SP(exp_W1, w1p,              4800, 300, 320, (size_t)4800 * 320, 2);
  SP(exp_W2, w2p,              2400, 600, 608, (size_t)2400 * 608, 2);

  // --- K1: whiten (3-plane math) -> xw 2-plane ---
  if (preX) {
    SP(x, xp3, NTOK, DIN_, DIN_, (size_t)NTOK * DIN_, 3);   // bit-identical planes
    dim3 g(5, NTOK / 128);
    mfma_gen<0, 5, 2, 4, 3, 2, 1><<<g, 256, 0, stream>>>(
        xp3, (size_t)NTOK * DIN_, 0, whp, (size_t)300 * 768, bp, nullptr,
        xwreg, (size_t)NTOK * 320, 320, nullptr, nullptr, nullptr,
        NTOK, D_, DIN_);
  } else {
    dim3 g(5, NTOK / 128);
    mfma_gen<1, 5, 2, 4, 3, 2, 1><<<g, 256, 0, stream>>>(
        x, 0, DIN_, whp, (size_t)300 * 768, bp, nullptr,
        xwreg, (size_t)NTOK * 320, 320, nullptr, nullptr, nullptr,
        NTOK, D_, DIN_);
  }
  // --- K2: fused QKV [NTOK][192], 2-plane both sides ---
  {
    dim3 g(3, NTOK / 128);
    mfma_gen<0, 0, 2, 4, 2, 2, 1><<<g, 256, 0, stream>>>(
        xwreg, (size_t)NTOK * 320, 0, qkvp, (size_t)192 * 320, nullptr, qkvb,
        nullptr, 0, 0, nullptr, nullptr, nullptr,
        NTOK, 192, D_);
  }
  // --- K3: attention (KV-shared blocks; att in-place over q part) ---
  attn_kernel<<<B_ * (T_ / TW), 64 * TW, 0, stream>>>(qkvb, qkvb);

  // --- K4: proj (3-plane math, AFP staging) -> xa fp32 + xa 2-plane ---
  {
    dim3 g(5, NTOK / 128);
    mfma_gen<1, 6, 2, 4, 3, 2, 1><<<g, 256, 0, stream>>>(
        qkvb, 0, 192, projp, (size_t)300 * 64, proj_b, xa,
        xap, (size_t)NTOK * 320, 320, nullptr, nullptr, nullptr,
        NTOK, D_, 64);
  }
  // --- K5/K6: gating ---
  logits_kernel<<<(NTOK * E_ + 255) / 256, 256, 0, stream>>>(xa, w_gate, gprob);
  gate_kernel<<<(NTOK + 255) / 256, 256, 0, stream>>>(gprob, gprob);

  // --- K7: experts (2-plane, r14 shapes + T1 swizzle); gsum in d_out ---
  for (int c = 0; c < NTOK / CHe; ++c) {
    const int tok0 = c * CHe;
    float* gsum = (float*)d_out + (size_t)tok0 * D_;
    dim3 g1(5, CHe / 128);   // G1: 128x128 tiles (JN=4), 32KB LDS
    dim3 g2(5, CHe / 128);   // G2: 128x64 tiles (JN=2), 24KB LDS
    for (int e = 0; e < E_; ++e) {
      const us* w1e = w1p + (size_t)e * 600 * 320;
      const us* w2e = w2p + (size_t)e * 300 * 608;
      const float* bb1 = exp_b1 + (size_t)e * 600;
      const float* bb2 = exp_b2 + (size_t)e * D_;
      const float* gate = gprob + (size_t)tok0 * E_ + e;
      // G1: h_2planes = split2(relu(xa @ W1^T + b1)), pads zeroed
      mfma_gen<0, 1, 4, 4, 2, 2, 1><<<g1, 256, 0, stream>>>(
          xap + (size_t)tok0 * 320, (size_t)NTOK * 320, 0,
          w1e, (size_t)4800 * 320, bb1, nullptr,
          hpl, (size_t)CHe * 608, 608, nullptr, nullptr, nullptr,
          CHe, 600, D_);
      // G2: eo = h @ W2^T + b2 folded into gsum/esum (final e writes out)
      if (e == 0)
        mfma_gen<0, 2, 2, 4, 2, 2, 1><<<g2, 256, 0, stream>>>(
            hpl, (size_t)CHe * 608, 0, w2e, (size_t)2400 * 608, bb2, nullptr,
            nullptr, 0, 0, gsum, esum, gate, CHe, D_, 600);
      else if (e < E_ - 1)
        mfma_gen<0, 3, 2, 4, 2, 2, 1><<<g2, 256, 0, stream>>>(
            hpl, (size_t)CHe * 608, 0, w2e, (size_t)2400 * 608, bb2, nullptr,
            nullptr, 0, 0, gsum, esum, gate, CHe, D_, 600);
      else
        mfma_gen<0, 4, 2, 4, 2, 2, 1><<<g2, 256, 0, stream>>>(
            hpl, (size_t)CHe * 608, 0, w2e, (size_t)2400 * 608, bb2,
            (float*)d_out + (size_t)tok0 * D_,
            nullptr, 0, 0, gsum, esum, gate, CHe, D_, 600);
    }
  }
}

// Round 18
// 964.251 us; speedup vs baseline: 1.0262x; 1.0262x over previous
//
#include <hip/hip_runtime.h>
#include <cstdint>
#include <cstddef>

#define B_   64
#define T_   300
#define DIN_ 768
#define D_   300
#define E_   8
#define NTOK (B_*T_)   // 19200
#define TW   6         // t's per attention block (6 waves; 300/6=50 chunks)
#define SC   32        // KV staging chunk rows

typedef __attribute__((ext_vector_type(8))) short bf8_t;           // 8 bf16 (4 VGPR)
typedef __attribute__((ext_vector_type(4))) float f4_t;            // 4 fp32 acc

__device__ __forceinline__ unsigned short f2bf(float v) {
  union { float f; unsigned u; } a; a.f = v;
  unsigned r = a.u + 0x7fff + ((a.u >> 16) & 1);   // RNE
  return (unsigned short)(r >> 16);
}
__device__ __forceinline__ float bf2f(unsigned short s) {
  union { float f; unsigned u; } a; a.u = ((unsigned)s) << 16; return a.f;
}
// v ~= p0 + p1 + p2 (24 mantissa bits)
__device__ __forceinline__ void split3(float v, unsigned short& p0,
                                       unsigned short& p1, unsigned short& p2) {
  p0 = f2bf(v);
  float r1 = v - bf2f(p0);
  p1 = f2bf(r1);
  float r2 = r1 - bf2f(p1);
  p2 = f2bf(r2);
}
// v ~= p0 + p1 (17 mantissa bits)
__device__ __forceinline__ void split2(float v, unsigned short& p0,
                                       unsigned short& p1) {
  p0 = f2bf(v);
  p1 = f2bf(v - bf2f(p0));
}

// direct global->LDS 16B DMA (width=16, m97/m151 pattern)
__device__ __forceinline__ void gld16(const unsigned short* g, unsigned short* l) {
  __builtin_amdgcn_global_load_lds(
      (const __attribute__((address_space(1))) unsigned int*)g,
      (__attribute__((address_space(3))) unsigned int*)l, 16, 0, 0);
}

// ---------------------------------------------------------------------------
__global__ void biasproj_kernel(const float* __restrict__ wh_bias,
                                const float* __restrict__ wh_W,
                                float* __restrict__ bp) {
  int o = blockIdx.x * blockDim.x + threadIdx.x;
  if (o >= D_) return;
  float acc = 0.f;
  const float* row = wh_W + (size_t)o * DIN_;
  for (int d = 0; d < DIN_; ++d) acc += wh_bias[d] * row[d];
  bp[o] = -acc;
}

// ---------------------------------------------------------------------------
// split fp32 [rows][K] -> np bf16 planes [rows][Kp], zero-padded cols
// ---------------------------------------------------------------------------
__global__ void split_pad(const float* __restrict__ src, unsigned short* __restrict__ dst,
                          int rows, int K, int Kp, size_t planeStride, int np) {
  int n = rows * Kp;
  for (int i = blockIdx.x * blockDim.x + threadIdx.x; i < n; i += gridDim.x * blockDim.x) {
    int r = i / Kp, c = i % Kp;
    unsigned short p0 = 0, p1 = 0, p2 = 0;
    if (c < K) split3(src[(size_t)r * K + c], p0, p1, p2);
    dst[i] = p0;
    dst[planeStride + i] = p1;
    if (np == 3) dst[2 * planeStride + i] = p2;
  }
}

// ---------------------------------------------------------------------------
// MFMA GEMM, fp32 emulated via NP bf16 planes (NP=3: 6 products; NP=2: 3).
// (r15-proven body: frag-reads -> barrier -> next-stage issue ∥ MFMA -> barrier)
// Staging: B (and A when AFP=0) via global_load_lds width-16 into LINEAR LDS
// [row][32 shorts], chunk-XOR swizzle c_phys = c_log ^ ((row>>1)&3) applied
// on SOURCE address and FRAG-READ address (both-sides rule).
// SWZ=1: bijective XCD-aware block remap (T1, m204 form).
// AFP=1: A fp32 split3-on-stage via ds_write (requires NP=3).
// EPI: 0 = C = acc (+bias)                    [fp32 out]
//      1 = planes(relu(acc+bias)) -> Po       [G1 -> h planes]
//      2 = gsum = g*eo, esum = eo             (eo = acc+bias)
//      3 = gsum += g*eo, esum += eo
//      4 = C = (gsum+g*eo)*(esum+eo)
//      5 = planes(acc+bias) -> Po             [whiten -> xw planes]
//      6 = C = acc+bias AND planes -> Po      [proj -> xa + xa planes]
// Plane epilogues ZERO pads for N <= col < ldPo (NaN*0=NaN downstream else).
// ---------------------------------------------------------------------------
template<int AFP, int EPI, int JN, int WM, int NP, int NPO, int SWZ>
__global__ __launch_bounds__(WM * 64) void mfma_gen(
    const void* __restrict__ Av, size_t aPStride, int ldA,
    const unsigned short* __restrict__ Bg, size_t bPStride,
    const float* __restrict__ bias, float* __restrict__ C,
    unsigned short* __restrict__ Po, size_t poStride, int ldPo,
    float* __restrict__ gsum, float* __restrict__ esum,
    const float* __restrict__ gate,
    int M, int N, int K) {
  constexpr int TILE_M = WM * 32;
  constexpr int BROWS  = JN * 32;
  constexpr int APB    = TILE_M * 64;        // bytes per A plane in LDS
  constexpr int BPB    = BROWS * 64;
  constexpr int AINSTS = NP * APB / 1024;    // gload_lds instrs for A
  constexpr int BINSTS = NP * BPB / 1024;
  static_assert(!AFP || NP == 3, "AFP path writes 3 planes");
  __shared__ unsigned short Ap[NP][TILE_M * 32];
  __shared__ unsigned short Bp[NP][BROWS * 32];
  const int tid = threadIdx.x;
  // block-id -> tile mapping (optionally XCD-swizzled, bijective for any nwg)
  int bxv = blockIdx.x, byv = blockIdx.y;
  if constexpr (SWZ) {
    const int nx  = gridDim.x;
    const int nwg = nx * gridDim.y;
    const int id  = byv * nx + bxv;
    const int xcd = id & 7, idx = id >> 3;
    const int q = nwg >> 3, r = nwg & 7;
    const int nid = (xcd < r) ? (xcd * (q + 1) + idx)
                              : (r * (q + 1) + (xcd - r) * q + idx);
    bxv = nid % nx;
    byv = nid / nx;
  }
  const int bm = byv * TILE_M, bn = bxv * BROWS;
  const int widx = tid >> 6;
  const int wr = (widx >> 1) * 64;           // 0 when WM=2
  const int wc = (widx & 1) * (JN * 16);
  const int lane = tid & 63;
  const int lr = lane & 15;
  const int kg = lane >> 4;
  const int sw = (lr >> 1) & 3;              // read-side chunk swizzle
  const int Kp = (K + 31) & ~31;
  // AFP staging map
  const int arow = tid >> 1, ahalf = (tid & 1) * 16;
  const int asw = (arow >> 1) & 3;

  auto stageB = [&](int k0) {
    for (int q = widx; q < BINSTS; q += WM) {
      const int f   = q * 1024 + lane * 16;
      const int pp  = f / BPB;
      const int rem = f % BPB;
      const int row = rem >> 6;
      const int cl  = ((rem >> 4) & 3) ^ ((row >> 1) & 3);
      int brow = bn + row; if (brow >= N) brow = N - 1;
      gld16(Bg + (size_t)pp * bPStride + (size_t)brow * Kp + k0 + cl * 8,
            (unsigned short*)Bp + q * 512);
    }
  };
  auto stageA = [&](int k0) {
    if constexpr (AFP) {
      const float* Arow = (const float*)Av + (size_t)(bm + arow) * ldA + k0 + ahalf;
      #pragma unroll
      for (int u = 0; u < 4; ++u) {
        float4 qv = *(const float4*)&Arow[u * 4];
        float vv[4] = {qv.x, qv.y, qv.z, qv.w};
        unsigned short s0[4], s1[4], s2[4];
        #pragma unroll
        for (int w = 0; w < 4; ++w) split3(vv[w], s0[w], s1[w], s2[w]);
        const int k  = ahalf + u * 4;
        const int so = arow * 32 + (((k >> 3) ^ asw) << 3) + (k & 7);
        *(unsigned*)&Ap[0][so]     = (unsigned)s0[0] | ((unsigned)s0[1] << 16);
        *(unsigned*)&Ap[0][so + 2] = (unsigned)s0[2] | ((unsigned)s0[3] << 16);
        *(unsigned*)&Ap[1][so]     = (unsigned)s1[0] | ((unsigned)s1[1] << 16);
        *(unsigned*)&Ap[1][so + 2] = (unsigned)s1[2] | ((unsigned)s1[3] << 16);
        *(unsigned*)&Ap[2][so]     = (unsigned)s2[0] | ((unsigned)s2[1] << 16);
        *(unsigned*)&Ap[2][so + 2] = (unsigned)s2[2] | ((unsigned)s2[3] << 16);
      }
    } else {
      for (int q = widx; q < AINSTS; q += WM) {
        const int f   = q * 1024 + lane * 16;
        const int pp  = f / APB;
        const int rem = f % APB;
        const int row = rem >> 6;
        const int cl  = ((rem >> 4) & 3) ^ ((row >> 1) & 3);
        gld16((const unsigned short*)Av + (size_t)pp * aPStride +
                  (size_t)(bm + row) * Kp + k0 + cl * 8,
              (unsigned short*)Ap + q * 512);
      }
    }
  };

  f4_t acc[4][JN];
  #pragma unroll
  for (int i = 0; i < 4; ++i)
    #pragma unroll
    for (int j = 0; j < JN; ++j) acc[i][j] = (f4_t){0.f, 0.f, 0.f, 0.f};

  stageB(0); stageA(0);
  __syncthreads();
  for (int k0 = 0; k0 < Kp; k0 += 32) {
    // ---- frag reads (swizzled) ----
    bf8_t a[4][NP], b[JN][NP];
    #pragma unroll
    for (int i = 0; i < 4; ++i)
      #pragma unroll
      for (int p = 0; p < NP; ++p)
        a[i][p] = *(const bf8_t*)&Ap[p][(wr + i * 16 + lr) * 32 + ((kg ^ sw) << 3)];
    #pragma unroll
    for (int j = 0; j < JN; ++j)
      #pragma unroll
      for (int p = 0; p < NP; ++p)
        b[j][p] = *(const bf8_t*)&Bp[p][(wc + j * 16 + lr) * 32 + ((kg ^ sw) << 3)];
    __syncthreads();   // all waves done reading -> LDS reusable
    if (k0 + 32 < Kp) { stageB(k0 + 32); stageA(k0 + 32); }   // fly under MFMA
    #pragma unroll
    for (int i = 0; i < 4; ++i)
      #pragma unroll
      for (int j = 0; j < JN; ++j) {
        f4_t c = acc[i][j];
        if constexpr (NP == 3) {
          c = __builtin_amdgcn_mfma_f32_16x16x32_bf16(a[i][2], b[j][0], c, 0, 0, 0);
          c = __builtin_amdgcn_mfma_f32_16x16x32_bf16(a[i][1], b[j][1], c, 0, 0, 0);
          c = __builtin_amdgcn_mfma_f32_16x16x32_bf16(a[i][0], b[j][2], c, 0, 0, 0);
          c = __builtin_amdgcn_mfma_f32_16x16x32_bf16(a[i][1], b[j][0], c, 0, 0, 0);
          c = __builtin_amdgcn_mfma_f32_16x16x32_bf16(a[i][0], b[j][1], c, 0, 0, 0);
          c = __builtin_amdgcn_mfma_f32_16x16x32_bf16(a[i][0], b[j][0], c, 0, 0, 0);
        } else {
          c = __builtin_amdgcn_mfma_f32_16x16x32_bf16(a[i][1], b[j][0], c, 0, 0, 0);
          c = __builtin_amdgcn_mfma_f32_16x16x32_bf16(a[i][0], b[j][1], c, 0, 0, 0);
          c = __builtin_amdgcn_mfma_f32_16x16x32_bf16(a[i][0], b[j][0], c, 0, 0, 0);
        }
        acc[i][j] = c;
      }
    __syncthreads();   // next stage drained (vmcnt+lgkm)
  }
  // ---- epilogue ----
  #pragma unroll
  for (int i = 0; i < 4; ++i) {
    #pragma unroll
    for (int r = 0; r < 4; ++r) {
      const int row = bm + wr + i * 16 + kg * 4 + r;
      float g = 0.f;
      if constexpr (EPI >= 2 && EPI <= 4) g = gate[(size_t)row * E_];
      #pragma unroll
      for (int j = 0; j < JN; ++j) {
        const int col = bn + wc + j * 16 + lr;
        float v = acc[i][j][r];
        if constexpr (EPI == 0) {
          if (col < N) {
            if (bias) v += bias[col];
            C[(size_t)row * N + col] = v;
          }
        } else if constexpr (EPI == 1 || EPI == 5 || EPI == 6) {
          if (col < ldPo) {
            unsigned short p0 = 0, p1 = 0, p2 = 0;
            if (col < N) {
              v += bias[col];
              if constexpr (EPI == 1) v = fmaxf(v, 0.f);
              if constexpr (EPI == 6) C[(size_t)row * N + col] = v;
              if constexpr (NPO == 3) split3(v, p0, p1, p2);
              else                    split2(v, p0, p1);
            }
            size_t o = (size_t)row * ldPo + col;
            Po[o] = p0;
            Po[poStride + o] = p1;
            if constexpr (NPO == 3) Po[2 * poStride + o] = p2;
          }
        } else {
          if (col < N) {
            float eo = v + bias[col];
            size_t idx = (size_t)row * N + col;
            if constexpr (EPI == 2) {
              gsum[idx] = g * eo;
              esum[idx] = eo;
            } else if constexpr (EPI == 3) {
              gsum[idx] += g * eo;
              esum[idx] += eo;
            } else {
              float gs = gsum[idx] + g * eo;
              float es = esum[idx] + eo;
              C[idx] = gs * es;
            }
          }
        }
      }
    }
  }
}

// ---------------------------------------------------------------------------
// Attention, KV-shared form (r17 structure, TW=6 for occupancy/reuse balance).
// One block = (batch b, 6 consecutive t's). 6 waves x 64 thr; wave w owns
// t = tch*6+w; 16 lanes per head; per-(wave,head) score rows p[TW][4][304].
// K (then V) staged in 32-row LDS chunks once per block; all 6 waves consume
// from LDS (6x less L2 traffic than per-(b,t) blocks). LDS 37.9KB ->
// 4 blocks/CU = 24 waves/CU. Accumulation order identical to round-11
// (chunk starts multiples of 4, same per-lane s assignment, same o0..o3
// striding) -> bit-identical output. att written in-place over own q rows.
// ---------------------------------------------------------------------------
__global__ __launch_bounds__(64 * TW) void attn_kernel(
    const float* __restrict__ qkv, float* __restrict__ attout) {
  const int nch_blk = T_ / TW;               // 50
  const int b   = blockIdx.x / nch_blk;
  const int tch = blockIdx.x % nch_blk;
  const int w    = threadIdx.x >> 6;
  const int lane = threadIdx.x & 63;
  const int h = lane >> 4, li = lane & 15;
  const int t    = tch * TW + w;
  const int tmax = tch * TW + TW - 1;
  __shared__ float kv[SC][68];               // K chunk, then reused for V
  __shared__ float p[TW][4][304];            // per-(wave, head) score rows
  const float scale = rsqrtf((float)D_);
  const float* base = qkv + (size_t)b * T_ * 192;
  const float* qrow = base + (size_t)t * 192 + h * 16;
  const float4 q0 = *(const float4*)(qrow);
  const float4 q1 = *(const float4*)(qrow + 4);
  const float4 q2 = *(const float4*)(qrow + 8);
  const float4 q3 = *(const float4*)(qrow + 12);
  const int nch = tmax / SC + 1;             // chunks covering s in [0, tmax]

  // ---- pass 1: K chunks -> scores in p[w][h][*], track per-lane max ----
  float mmax = -1e30f;
  for (int c = 0; c < nch; ++c) {
    const int s0 = c * SC;
    __syncthreads();                          // prior chunk fully consumed
    for (int i = threadIdx.x; i < SC * 16; i += 64 * TW) {
      const int r = i >> 4, c4 = (i & 15) * 4;
      int sr = s0 + r; if (sr > T_ - 1) sr = T_ - 1;   // clamped rows unused
      *(float4*)&kv[r][c4] = *(const float4*)&base[(size_t)sr * 192 + 64 + c4];
    }
    __syncthreads();
    const int send = (s0 + SC - 1 < t) ? s0 + SC - 1 : t;
    for (int s = s0 + li; s <= send; s += 16) {
      const float* kr = &kv[s - s0][h * 16];
      float4 k0 = *(const float4*)(kr);
      float4 k1 = *(const float4*)(kr + 4);
      float4 k2 = *(const float4*)(kr + 8);
      float4 k3 = *(const float4*)(kr + 12);
      float acc = q0.x * k0.x + q0.y * k0.y + q0.z * k0.z + q0.w * k0.w;
      acc += q1.x * k1.x + q1.y * k1.y + q1.z * k1.z + q1.w * k1.w;
      acc += q2.x * k2.x + q2.y * k2.y + q2.z * k2.z + q2.w * k2.w;
      acc += q3.x * k3.x + q3.y * k3.y + q3.z * k3.z + q3.w * k3.w;
      acc *= scale;
      p[w][h][s] = acc;
      mmax = fmaxf(mmax, acc);
    }
  }
  // ---- softmax (own (w,h) rows; 16-lane reduction as r11) ----
  #pragma unroll
  for (int m = 8; m >= 1; m >>= 1) mmax = fmaxf(mmax, __shfl_xor(mmax, m, 16));
  float lsum = 0.f;
  for (int s = li; s <= t; s += 16) {
    float e = __expf(p[w][h][s] - mmax);
    p[w][h][s] = e;
    lsum += e;
  }
  #pragma unroll
  for (int m = 8; m >= 1; m >>= 1) lsum += __shfl_xor(lsum, m, 16);
  const float inv = 1.0f / lsum;

  // ---- pass 2: V chunks -> PV accumulate (r11 order preserved) ----
  float o0 = 0.f, o1 = 0.f, o2 = 0.f, o3 = 0.f;
  for (int c = 0; c < nch; ++c) {
    const int s0 = c * SC;
    __syncthreads();                          // K/prev-V reads done
    for (int i = threadIdx.x; i < SC * 16; i += 64 * TW) {
      const int r = i >> 4, c4 = (i & 15) * 4;
      int sr = s0 + r; if (sr > T_ - 1) sr = T_ - 1;
      *(float4*)&kv[r][c4] = *(const float4*)&base[(size_t)sr * 192 + 128 + c4];
    }
    __syncthreads();
    const int send = (s0 + SC - 1 < t) ? s0 + SC - 1 : t;
    const int col = h * 16 + li;
    int s = s0;
    for (; s + 3 <= send; s += 4) {
      float4 pw = *(const float4*)&p[w][h][s];
      o0 += pw.x * kv[s - s0][col];
      o1 += pw.y * kv[s + 1 - s0][col];
      o2 += pw.z * kv[s + 2 - s0][col];
      o3 += pw.w * kv[s + 3 - s0][col];
    }
    for (; s <= send; ++s) o0 += p[w][h][s] * kv[s - s0][col];
  }
  attout[((size_t)b * T_ + t) * 192 + lane] = ((o0 + o1) + (o2 + o3)) * inv;
}

// ---------------------------------------------------------------------------
__global__ void logits_kernel(const float* __restrict__ xa,
                              const float* __restrict__ w_gate,
                              float* __restrict__ logits) {
  int idx = blockIdx.x * blockDim.x + threadIdx.x;
  if (idx >= NTOK * E_) return;
  int n = idx >> 3, e = idx & 7;
  const float* xr = xa + (size_t)n * D_;
  float acc = 0.f;
  for (int d = 0; d < D_; ++d) acc += xr[d] * w_gate[(size_t)d * E_ + e];
  logits[idx] = acc;
}

// ---------------------------------------------------------------------------
__global__ void gate_kernel(const float* __restrict__ logits,
                            float* __restrict__ gprob) {
  int n = blockIdx.x * blockDim.x + threadIdx.x;
  if (n >= NTOK) return;
  float l[E_];
  #pragma unroll
  for (int e = 0; e < E_; ++e) l[e] = logits[(size_t)n * E_ + e];
  bool sel[E_] = {false, false, false, false, false, false, false, false};
  for (int kk = 0; kk < E_ / 2; ++kk) {
    int bi = -1; float bv = -1e38f;
    #pragma unroll
    for (int e = 0; e < E_; ++e)
      if (!sel[e] && l[e] > bv) { bv = l[e]; bi = e; }
    sel[bi] = true;
  }
  float mx = -1e38f;
  #pragma unroll
  for (int e = 0; e < E_; ++e) if (sel[e]) mx = fmaxf(mx, l[e]);
  float s = 0.f, pp[E_];
  #pragma unroll
  for (int e = 0; e < E_; ++e) {
    pp[e] = sel[e] ? __expf(l[e] - mx) : 0.f;
    s += pp[e];
  }
  float inv = 1.0f / s;
  #pragma unroll
  for (int e = 0; e < E_; ++e) gprob[(size_t)n * E_ + e] = pp[e] * inv;
}

// ---------------------------------------------------------------------------
extern "C" void kernel_launch(void* const* d_in, const int* in_sizes, int n_in,
                              void* d_out, int out_size, void* d_ws, size_t ws_size,
                              hipStream_t stream) {
  const float* x       = (const float*)d_in[0];
  const float* wh_bias = (const float*)d_in[1];
  const float* wh_W    = (const float*)d_in[2];
  const float* Wq      = (const float*)d_in[3];
  const float* Wk      = (const float*)d_in[4];
  const float* Wv      = (const float*)d_in[5];
  const float* proj_W  = (const float*)d_in[6];
  const float* proj_b  = (const float*)d_in[7];
  const float* exp_W1  = (const float*)d_in[8];
  const float* exp_b1  = (const float*)d_in[9];
  const float* exp_W2  = (const float*)d_in[10];
  const float* exp_b2  = (const float*)d_in[11];
  const float* w_gate  = (const float*)d_in[12];
  (void)in_sizes; (void)n_in; (void)out_size;

  char* ws = (char*)d_ws;
  size_t off = 0;
  auto alloc = [&](size_t bytes) {
    void* p = ws + off; off = (off + bytes + 255) & ~(size_t)255; return p;
  };
  typedef unsigned short us;
  float* bp    = (float*)alloc(300 * 4);
  us* whp      = (us*)alloc((size_t)3 * 300 * 768 * 2);          // 3-plane, Kp=768
  us* qkvp     = (us*)alloc((size_t)2 * 192 * 320 * 2);          // 2-plane, Kp=320
  us* projp    = (us*)alloc((size_t)3 * 300 * 64 * 2);           // 3-plane, Kp=64
  us* w1p      = (us*)alloc((size_t)2 * 4800 * 320 * 2);         // 2-plane, Kp=320
  us* w2p      = (us*)alloc(((size_t)2 * 2400 * 608 + 64 * 608) * 2);  // 2-plane +guard
  float* gprob = (float*)alloc((size_t)NTOK * E_ * 4);
  us* xwreg    = (us*)alloc((size_t)2 * NTOK * 320 * 2);   // xw 2-plane / xa fp32 / h (fb)
  float* qkvb  = (float*)alloc((size_t)NTOK * 192 * 4);    // qkv+att; esum (fallback)
  us* xap      = (us*)alloc((size_t)2 * NTOK * 320 * 2);   // xa 2-plane
  // base total ~78 MB. gsum always lives in d_out.

  float* xa = (float*)xwreg;         // [NTOK][300] fp32; dead after gating

  // region plan:
  //  preX: one region of 88.5MB serves x 3-planes (whiten) THEN hpl+esum
  //  else: dedicated hpl+esum (70MB) if it fits; else r11 aliases (CH=9600)
  const size_t xp3Bytes  = (size_t)3 * NTOK * DIN_ * 2;  // 88.5 MB
  const size_t hplBytes  = (size_t)2 * NTOK * 608 * 2;   // 46.7 MB
  const size_t esumBytes = (size_t)NTOK * 300 * 4;       // 23.0 MB
  const size_t hplAl = (hplBytes + 255) & ~(size_t)255;
  int CHe;
  us* hpl;
  float* esum;
  us* xp3 = nullptr;
  bool preX = false;
  if (off + xp3Bytes <= ws_size) {
    char* region = ws + off;
    off += (xp3Bytes + 255) & ~(size_t)255;
    xp3  = (us*)region;                       // whiten phase
    hpl  = (us*)region;                       // expert phase (xp3 dead)
    esum = (float*)(region + hplAl);
    CHe  = NTOK;
    preX = true;
  } else if (off + hplBytes + esumBytes <= ws_size) {
    hpl  = (us*)alloc(hplBytes);
    esum = (float*)alloc(esumBytes);
    CHe  = NTOK;
  } else {
    hpl  = xwreg;                    // 23.3MB <= 24.58MB
    esum = qkvb;                     // 11.5MB <= 14.75MB
    CHe  = 9600;
  }

  // --- weight pre-split ---
  biasproj_kernel<<<2, 256, 0, stream>>>(wh_bias, wh_W, bp);
  auto SP = [&](const float* s, us* dbase, int rows, int K, int Kp, size_t pstr, int np) {
    int n = rows * Kp;
    int g = (n + 255) / 256; if (g > 4096) g = 4096;
    split_pad<<<g, 256, 0, stream>>>(s, dbase, rows, K, Kp, pstr, np);
  };
  SP(wh_W,   whp,              300,  768, 768, (size_t)300 * 768, 3);
  SP(Wq,     qkvp,             64,   300, 320, (size_t)192 * 320, 2);
  SP(Wk,     qkvp + 64 * 320,  64,   300, 320, (size_t)192 * 320, 2);
  SP(Wv,     qkvp + 128 * 320, 64,   300, 320, (size_t)192 * 320, 2);
  SP(proj_W, projp,            300,  64,  64,  (size_t)300 * 64, 3);
  SP(exp_W1, w1p,              4800, 300, 320, (size_t)4800 * 320, 2);
  SP(exp_W2, w2p,              2400, 600, 608, (size_t)2400 * 608, 2);

  // --- K1: whiten (3-plane math) -> xw 2-plane ---
  if (preX) {
    SP(x, xp3, NTOK, DIN_, DIN_, (size_t)NTOK * DIN_, 3);   // bit-identical planes
    dim3 g(5, NTOK / 128);
    mfma_gen<0, 5, 2, 4, 3, 2, 1><<<g, 256, 0, stream>>>(
        xp3, (size_t)NTOK * DIN_, 0, whp, (size_t)300 * 768, bp, nullptr,
        xwreg, (size_t)NTOK * 320, 320, nullptr, nullptr, nullptr,
        NTOK, D_, DIN_);
  } else {
    dim3 g(5, NTOK / 128);
    mfma_gen<1, 5, 2, 4, 3, 2, 1><<<g, 256, 0, stream>>>(
        x, 0, DIN_, whp, (size_t)300 * 768, bp, nullptr,
        xwreg, (size_t)NTOK * 320, 320, nullptr, nullptr, nullptr,
        NTOK, D_, DIN_);
  }
  // --- K2: fused QKV [NTOK][192], 2-plane both sides ---
  {
    dim3 g(3, NTOK / 128);
    mfma_gen<0, 0, 2, 4, 2, 2, 1><<<g, 256, 0, stream>>>(
        xwreg, (size_t)NTOK * 320, 0, qkvp, (size_t)192 * 320, nullptr, qkvb,
        nullptr, 0, 0, nullptr, nullptr, nullptr,
        NTOK, 192, D_);
  }
  // --- K3: attention (KV-shared blocks; att in-place over q part) ---
  attn_kernel<<<B_ * (T_ / TW), 64 * TW, 0, stream>>>(qkvb, qkvb);

  // --- K4: proj (3-plane math, AFP staging) -> xa fp32 + xa 2-plane ---
  {
    dim3 g(5, NTOK / 128);
    mfma_gen<1, 6, 2, 4, 3, 2, 1><<<g, 256, 0, stream>>>(
        qkvb, 0, 192, projp, (size_t)300 * 64, proj_b, xa,
        xap, (size_t)NTOK * 320, 320, nullptr, nullptr, nullptr,
        NTOK, D_, 64);
  }
  // --- K5/K6: gating ---
  logits_kernel<<<(NTOK * E_ + 255) / 256, 256, 0, stream>>>(xa, w_gate, gprob);
  gate_kernel<<<(NTOK + 255) / 256, 256, 0, stream>>>(gprob, gprob);

  // --- K7: experts (2-plane, r14 shapes + T1 swizzle); gsum in d_out ---
  for (int c = 0; c < NTOK / CHe; ++c) {
    const int tok0 = c * CHe;
    float* gsum = (float*)d_out + (size_t)tok0 * D_;
    dim3 g1(5, CHe / 128);   // G1: 128x128 tiles (JN=4), 32KB LDS
    dim3 g2(5, CHe / 128);   // G2: 128x64 tiles (JN=2), 24KB LDS
    for (int e = 0; e < E_; ++e) {
      const us* w1e = w1p + (size_t)e * 600 * 320;
      const us* w2e = w2p + (size_t)e * 300 * 608;
      const float* bb1 = exp_b1 + (size_t)e * 600;
      const float* bb2 = exp_b2 + (size_t)e * D_;
      const float* gate = gprob + (size_t)tok0 * E_ + e;
      // G1: h_2planes = split2(relu(xa @ W1^T + b1)), pads zeroed
      mfma_gen<0, 1, 4, 4, 2, 2, 1><<<g1, 256, 0, stream>>>(
          xap + (size_t)tok0 * 320, (size_t)NTOK * 320, 0,
          w1e, (size_t)4800 * 320, bb1, nullptr,
          hpl, (size_t)CHe * 608, 608, nullptr, nullptr, nullptr,
          CHe, 600, D_);
      // G2: eo = h @ W2^T + b2 folded into gsum/esum (final e writes out)
      if (e == 0)
        mfma_gen<0, 2, 2, 4, 2, 2, 1><<<g2, 256, 0, stream>>>(
            hpl, (size_t)CHe * 608, 0, w2e, (size_t)2400 * 608, bb2, nullptr,
            nullptr, 0, 0, gsum, esum, gate, CHe, D_, 600);
      else if (e < E_ - 1)
        mfma_gen<0, 3, 2, 4, 2, 2, 1><<<g2, 256, 0, stream>>>(
            hpl, (size_t)CHe * 608, 0, w2e, (size_t)2400 * 608, bb2, nullptr,
            nullptr, 0, 0, gsum, esum, gate, CHe, D_, 600);
      else
        mfma_gen<0, 4, 2, 4, 2, 2, 1><<<g2, 256, 0, stream>>>(
            hpl, (size_t)CHe * 608, 0, w2e, (size_t)2400 * 608, bb2,
            (float*)d_out + (size_t)tok0 * D_,
            nullptr, 0, 0, gsum, esum, gate, CHe, D_, 600);
    }
  }
}

// Round 19
// 901.438 us; speedup vs baseline: 1.0977x; 1.0697x over previous
//
#include <hip/hip_runtime.h>
#include <cstdint>
#include <cstddef>

#define B_   64
#define T_   300
#define DIN_ 768
#define D_   300
#define E_   8
#define NTOK (B_*T_)   // 19200
#define TW   6         // t's per attention block (6 waves)
#define SC   32        // KV staging chunk rows

typedef __attribute__((ext_vector_type(8))) short bf8_t;           // 8 bf16 (4 VGPR)
typedef __attribute__((ext_vector_type(4))) float f4_t;            // 4 fp32 acc

__device__ __forceinline__ unsigned short f2bf(float v) {
  union { float f; unsigned u; } a; a.f = v;
  unsigned r = a.u + 0x7fff + ((a.u >> 16) & 1);   // RNE
  return (unsigned short)(r >> 16);
}
__device__ __forceinline__ float bf2f(unsigned short s) {
  union { float f; unsigned u; } a; a.u = ((unsigned)s) << 16; return a.f;
}
// v ~= p0 + p1 + p2 (24 mantissa bits)
__device__ __forceinline__ void split3(float v, unsigned short& p0,
                                       unsigned short& p1, unsigned short& p2) {
  p0 = f2bf(v);
  float r1 = v - bf2f(p0);
  p1 = f2bf(r1);
  float r2 = r1 - bf2f(p1);
  p2 = f2bf(r2);
}
// v ~= p0 + p1 (17 mantissa bits)
__device__ __forceinline__ void split2(float v, unsigned short& p0,
                                       unsigned short& p1) {
  p0 = f2bf(v);
  p1 = f2bf(v - bf2f(p0));
}

// direct global->LDS 16B DMA (width=16, m97/m151 pattern)
__device__ __forceinline__ void gld16(const unsigned short* g, unsigned short* l) {
  __builtin_amdgcn_global_load_lds(
      (const __attribute__((address_space(1))) unsigned int*)g,
      (__attribute__((address_space(3))) unsigned int*)l, 16, 0, 0);
}

// ---------------------------------------------------------------------------
__global__ void biasproj_kernel(const float* __restrict__ wh_bias,
                                const float* __restrict__ wh_W,
                                float* __restrict__ bp) {
  int o = blockIdx.x * blockDim.x + threadIdx.x;
  if (o >= D_) return;
  float acc = 0.f;
  const float* row = wh_W + (size_t)o * DIN_;
  for (int d = 0; d < DIN_; ++d) acc += wh_bias[d] * row[d];
  bp[o] = -acc;
}

// ---------------------------------------------------------------------------
// split fp32 [rows][K] -> np bf16 planes [rows][Kp], zero-padded cols
// ---------------------------------------------------------------------------
__global__ void split_pad(const float* __restrict__ src, unsigned short* __restrict__ dst,
                          int rows, int K, int Kp, size_t planeStride, int np) {
  int n = rows * Kp;
  for (int i = blockIdx.x * blockDim.x + threadIdx.x; i < n; i += gridDim.x * blockDim.x) {
    int r = i / Kp, c = i % Kp;
    unsigned short p0 = 0, p1 = 0, p2 = 0;
    if (c < K) split3(src[(size_t)r * K + c], p0, p1, p2);
    dst[i] = p0;
    dst[planeStride + i] = p1;
    if (np == 3) dst[2 * planeStride + i] = p2;
  }
}

// ---------------------------------------------------------------------------
// MFMA GEMM, fp32 emulated via NP bf16 planes (NP=3: 6 products; NP=2: 3).
// (r15-proven body: frag-reads -> barrier -> next-stage issue ∥ MFMA -> barrier)
// Staging: B (and A when AFP=0) via global_load_lds width-16 into LINEAR LDS
// [row][32 shorts], chunk-XOR swizzle c_phys = c_log ^ ((row>>1)&3) applied
// on SOURCE address and FRAG-READ address (both-sides rule).
// SWZ=1: bijective XCD-aware block remap (T1, m204 form).
// AFP=1: A fp32 split-on-stage via ds_write (split3 for NP=3, split2 for NP=2).
// EPI: 0 = C = acc (+bias)                    [fp32 out]
//      1 = planes(relu(acc+bias)) -> Po       [G1 -> h planes]
//      2 = gsum = g*eo, esum = eo             (eo = acc+bias)
//      3 = gsum += g*eo, esum += eo
//      4 = C = (gsum+g*eo)*(esum+eo)
//      5 = planes(acc+bias) -> Po             [whiten -> xw planes]
//      6 = C = acc+bias AND planes -> Po      [proj -> xa + xa planes]
// Plane epilogues ZERO pads for N <= col < ldPo (NaN*0=NaN downstream else).
// ---------------------------------------------------------------------------
template<int AFP, int EPI, int JN, int WM, int NP, int NPO, int SWZ>
__global__ __launch_bounds__(WM * 64) void mfma_gen(
    const void* __restrict__ Av, size_t aPStride, int ldA,
    const unsigned short* __restrict__ Bg, size_t bPStride,
    const float* __restrict__ bias, float* __restrict__ C,
    unsigned short* __restrict__ Po, size_t poStride, int ldPo,
    float* __restrict__ gsum, float* __restrict__ esum,
    const float* __restrict__ gate,
    int M, int N, int K) {
  constexpr int TILE_M = WM * 32;
  constexpr int BROWS  = JN * 32;
  constexpr int APB    = TILE_M * 64;        // bytes per A plane in LDS
  constexpr int BPB    = BROWS * 64;
  constexpr int AINSTS = NP * APB / 1024;    // gload_lds instrs for A
  constexpr int BINSTS = NP * BPB / 1024;
  __shared__ unsigned short Ap[NP][TILE_M * 32];
  __shared__ unsigned short Bp[NP][BROWS * 32];
  const int tid = threadIdx.x;
  // block-id -> tile mapping (optionally XCD-swizzled, bijective for any nwg)
  int bxv = blockIdx.x, byv = blockIdx.y;
  if constexpr (SWZ) {
    const int nx  = gridDim.x;
    const int nwg = nx * gridDim.y;
    const int id  = byv * nx + bxv;
    const int xcd = id & 7, idx = id >> 3;
    const int q = nwg >> 3, r = nwg & 7;
    const int nid = (xcd < r) ? (xcd * (q + 1) + idx)
                              : (r * (q + 1) + (xcd - r) * q + idx);
    bxv = nid % nx;
    byv = nid / nx;
  }
  const int bm = byv * TILE_M, bn = bxv * BROWS;
  const int widx = tid >> 6;
  const int wr = (widx >> 1) * 64;           // 0 when WM=2
  const int wc = (widx & 1) * (JN * 16);
  const int lane = tid & 63;
  const int lr = lane & 15;
  const int kg = lane >> 4;
  const int sw = (lr >> 1) & 3;              // read-side chunk swizzle
  const int Kp = (K + 31) & ~31;
  // AFP staging map
  const int arow = tid >> 1, ahalf = (tid & 1) * 16;
  const int asw = (arow >> 1) & 3;

  auto stageB = [&](int k0) {
    for (int q = widx; q < BINSTS; q += WM) {
      const int f   = q * 1024 + lane * 16;
      const int pp  = f / BPB;
      const int rem = f % BPB;
      const int row = rem >> 6;
      const int cl  = ((rem >> 4) & 3) ^ ((row >> 1) & 3);
      int brow = bn + row; if (brow >= N) brow = N - 1;
      gld16(Bg + (size_t)pp * bPStride + (size_t)brow * Kp + k0 + cl * 8,
            (unsigned short*)Bp + q * 512);
    }
  };
  auto stageA = [&](int k0) {
    if constexpr (AFP) {
      const float* Arow = (const float*)Av + (size_t)(bm + arow) * ldA + k0 + ahalf;
      #pragma unroll
      for (int u = 0; u < 4; ++u) {
        float4 qv = *(const float4*)&Arow[u * 4];
        float vv[4] = {qv.x, qv.y, qv.z, qv.w};
        unsigned short s0[4], s1[4], s2[4];
        #pragma unroll
        for (int w = 0; w < 4; ++w) {
          if constexpr (NP == 3) split3(vv[w], s0[w], s1[w], s2[w]);
          else                   split2(vv[w], s0[w], s1[w]);
        }
        const int k  = ahalf + u * 4;
        const int so = arow * 32 + (((k >> 3) ^ asw) << 3) + (k & 7);
        *(unsigned*)&Ap[0][so]     = (unsigned)s0[0] | ((unsigned)s0[1] << 16);
        *(unsigned*)&Ap[0][so + 2] = (unsigned)s0[2] | ((unsigned)s0[3] << 16);
        *(unsigned*)&Ap[1][so]     = (unsigned)s1[0] | ((unsigned)s1[1] << 16);
        *(unsigned*)&Ap[1][so + 2] = (unsigned)s1[2] | ((unsigned)s1[3] << 16);
        if constexpr (NP == 3) {
          *(unsigned*)&Ap[2][so]     = (unsigned)s2[0] | ((unsigned)s2[1] << 16);
          *(unsigned*)&Ap[2][so + 2] = (unsigned)s2[2] | ((unsigned)s2[3] << 16);
        }
      }
    } else {
      for (int q = widx; q < AINSTS; q += WM) {
        const int f   = q * 1024 + lane * 16;
        const int pp  = f / APB;
        const int rem = f % APB;
        const int row = rem >> 6;
        const int cl  = ((rem >> 4) & 3) ^ ((row >> 1) & 3);
        gld16((const unsigned short*)Av + (size_t)pp * aPStride +
                  (size_t)(bm + row) * Kp + k0 + cl * 8,
              (unsigned short*)Ap + q * 512);
      }
    }
  };

  f4_t acc[4][JN];
  #pragma unroll
  for (int i = 0; i < 4; ++i)
    #pragma unroll
    for (int j = 0; j < JN; ++j) acc[i][j] = (f4_t){0.f, 0.f, 0.f, 0.f};

  stageB(0); stageA(0);
  __syncthreads();
  for (int k0 = 0; k0 < Kp; k0 += 32) {
    // ---- frag reads (swizzled) ----
    bf8_t a[4][NP], b[JN][NP];
    #pragma unroll
    for (int i = 0; i < 4; ++i)
      #pragma unroll
      for (int p = 0; p < NP; ++p)
        a[i][p] = *(const bf8_t*)&Ap[p][(wr + i * 16 + lr) * 32 + ((kg ^ sw) << 3)];
    #pragma unroll
    for (int j = 0; j < JN; ++j)
      #pragma unroll
      for (int p = 0; p < NP; ++p)
        b[j][p] = *(const bf8_t*)&Bp[p][(wc + j * 16 + lr) * 32 + ((kg ^ sw) << 3)];
    __syncthreads();   // all waves done reading -> LDS reusable
    if (k0 + 32 < Kp) { stageB(k0 + 32); stageA(k0 + 32); }   // fly under MFMA
    #pragma unroll
    for (int i = 0; i < 4; ++i)
      #pragma unroll
      for (int j = 0; j < JN; ++j) {
        f4_t c = acc[i][j];
        if constexpr (NP == 3) {
          c = __builtin_amdgcn_mfma_f32_16x16x32_bf16(a[i][2], b[j][0], c, 0, 0, 0);
          c = __builtin_amdgcn_mfma_f32_16x16x32_bf16(a[i][1], b[j][1], c, 0, 0, 0);
          c = __builtin_amdgcn_mfma_f32_16x16x32_bf16(a[i][0], b[j][2], c, 0, 0, 0);
          c = __builtin_amdgcn_mfma_f32_16x16x32_bf16(a[i][1], b[j][0], c, 0, 0, 0);
          c = __builtin_amdgcn_mfma_f32_16x16x32_bf16(a[i][0], b[j][1], c, 0, 0, 0);
          c = __builtin_amdgcn_mfma_f32_16x16x32_bf16(a[i][0], b[j][0], c, 0, 0, 0);
        } else {
          c = __builtin_amdgcn_mfma_f32_16x16x32_bf16(a[i][1], b[j][0], c, 0, 0, 0);
          c = __builtin_amdgcn_mfma_f32_16x16x32_bf16(a[i][0], b[j][1], c, 0, 0, 0);
          c = __builtin_amdgcn_mfma_f32_16x16x32_bf16(a[i][0], b[j][0], c, 0, 0, 0);
        }
        acc[i][j] = c;
      }
    __syncthreads();   // next stage drained (vmcnt+lgkm)
  }
  // ---- epilogue ----
  #pragma unroll
  for (int i = 0; i < 4; ++i) {
    #pragma unroll
    for (int r = 0; r < 4; ++r) {
      const int row = bm + wr + i * 16 + kg * 4 + r;
      float g = 0.f;
      if constexpr (EPI >= 2 && EPI <= 4) g = gate[(size_t)row * E_];
      #pragma unroll
      for (int j = 0; j < JN; ++j) {
        const int col = bn + wc + j * 16 + lr;
        float v = acc[i][j][r];
        if constexpr (EPI == 0) {
          if (col < N) {
            if (bias) v += bias[col];
            C[(size_t)row * N + col] = v;
          }
        } else if constexpr (EPI == 1 || EPI == 5 || EPI == 6) {
          if (col < ldPo) {
            unsigned short p0 = 0, p1 = 0, p2 = 0;
            if (col < N) {
              v += bias[col];
              if constexpr (EPI == 1) v = fmaxf(v, 0.f);
              if constexpr (EPI == 6) C[(size_t)row * N + col] = v;
              if constexpr (NPO == 3) split3(v, p0, p1, p2);
              else                    split2(v, p0, p1);
            }
            size_t o = (size_t)row * ldPo + col;
            Po[o] = p0;
            Po[poStride + o] = p1;
            if constexpr (NPO == 3) Po[2 * poStride + o] = p2;
          }
        } else {
          if (col < N) {
            float eo = v + bias[col];
            size_t idx = (size_t)row * N + col;
            if constexpr (EPI == 2) {
              gsum[idx] = g * eo;
              esum[idx] = eo;
            } else if constexpr (EPI == 3) {
              gsum[idx] += g * eo;
              esum[idx] += eo;
            } else {
              float gs = gsum[idx] + g * eo;
              float es = esum[idx] + eo;
              C[idx] = gs * es;
            }
          }
        }
      }
    }
  }
}

// ---------------------------------------------------------------------------
// Attention, KV-shared form (r18 proven: TW=6, SC=32, p[TW][4][304]).
// ---------------------------------------------------------------------------
__global__ __launch_bounds__(64 * TW) void attn_kernel(
    const float* __restrict__ qkv, float* __restrict__ attout) {
  const int nch_blk = T_ / TW;               // 50
  const int b   = blockIdx.x / nch_blk;
  const int tch = blockIdx.x % nch_blk;
  const int w    = threadIdx.x >> 6;
  const int lane = threadIdx.x & 63;
  const int h = lane >> 4, li = lane & 15;
  const int t    = tch * TW + w;
  const int tmax = tch * TW + TW - 1;
  __shared__ float kv[SC][68];               // K chunk, then reused for V
  __shared__ float p[TW][4][304];            // per-(wave, head) score rows
  const float scale = rsqrtf((float)D_);
  const float* base = qkv + (size_t)b * T_ * 192;
  const float* qrow = base + (size_t)t * 192 + h * 16;
  const float4 q0 = *(const float4*)(qrow);
  const float4 q1 = *(const float4*)(qrow + 4);
  const float4 q2 = *(const float4*)(qrow + 8);
  const float4 q3 = *(const float4*)(qrow + 12);
  const int nch = tmax / SC + 1;             // chunks covering s in [0, tmax]

  // ---- pass 1: K chunks -> scores in p[w][h][*], track per-lane max ----
  float mmax = -1e30f;
  for (int c = 0; c < nch; ++c) {
    const int s0 = c * SC;
    __syncthreads();                          // prior chunk fully consumed
    for (int i = threadIdx.x; i < SC * 16; i += 64 * TW) {
      const int r = i >> 4, c4 = (i & 15) * 4;
      int sr = s0 + r; if (sr > T_ - 1) sr = T_ - 1;   // clamped rows unused
      *(float4*)&kv[r][c4] = *(const float4*)&base[(size_t)sr * 192 + 64 + c4];
    }
    __syncthreads();
    const int send = (s0 + SC - 1 < t) ? s0 + SC - 1 : t;
    for (int s = s0 + li; s <= send; s += 16) {
      const float* kr = &kv[s - s0][h * 16];
      float4 k0 = *(const float4*)(kr);
      float4 k1 = *(const float4*)(kr + 4);
      float4 k2 = *(const float4*)(kr + 8);
      float4 k3 = *(const float4*)(kr + 12);
      float acc = q0.x * k0.x + q0.y * k0.y + q0.z * k0.z + q0.w * k0.w;
      acc += q1.x * k1.x + q1.y * k1.y + q1.z * k1.z + q1.w * k1.w;
      acc += q2.x * k2.x + q2.y * k2.y + q2.z * k2.z + q2.w * k2.w;
      acc += q3.x * k3.x + q3.y * k3.y + q3.z * k3.z + q3.w * k3.w;
      acc *= scale;
      p[w][h][s] = acc;
      mmax = fmaxf(mmax, acc);
    }
  }
  // ---- softmax (own (w,h) rows; 16-lane reduction as r11) ----
  #pragma unroll
  for (int m = 8; m >= 1; m >>= 1) mmax = fmaxf(mmax, __shfl_xor(mmax, m, 16));
  float lsum = 0.f;
  for (int s = li; s <= t; s += 16) {
    float e = __expf(p[w][h][s] - mmax);
    p[w][h][s] = e;
    lsum += e;
  }
  #pragma unroll
  for (int m = 8; m >= 1; m >>= 1) lsum += __shfl_xor(lsum, m, 16);
  const float inv = 1.0f / lsum;

  // ---- pass 2: V chunks -> PV accumulate (r11 order preserved) ----
  float o0 = 0.f, o1 = 0.f, o2 = 0.f, o3 = 0.f;
  for (int c = 0; c < nch; ++c) {
    const int s0 = c * SC;
    __syncthreads();                          // K/prev-V reads done
    for (int i = threadIdx.x; i < SC * 16; i += 64 * TW) {
      const int r = i >> 4, c4 = (i & 15) * 4;
      int sr = s0 + r; if (sr > T_ - 1) sr = T_ - 1;
      *(float4*)&kv[r][c4] = *(const float4*)&base[(size_t)sr * 192 + 128 + c4];
    }
    __syncthreads();
    const int send = (s0 + SC - 1 < t) ? s0 + SC - 1 : t;
    const int col = h * 16 + li;
    int s = s0;
    for (; s + 3 <= send; s += 4) {
      float4 pw = *(const float4*)&p[w][h][s];
      o0 += pw.x * kv[s - s0][col];
      o1 += pw.y * kv[s + 1 - s0][col];
      o2 += pw.z * kv[s + 2 - s0][col];
      o3 += pw.w * kv[s + 3 - s0][col];
    }
    for (; s <= send; ++s) o0 += p[w][h][s] * kv[s - s0][col];
  }
  attout[((size_t)b * T_ + t) * 192 + lane] = ((o0 + o1) + (o2 + o3)) * inv;
}

// ---------------------------------------------------------------------------
// Fused gating: logits (same accumulation order as before) + top-4 softmax.
// One thread per token; xa row streamed ONCE (was 8x); w_gate L1-cached.
// ---------------------------------------------------------------------------
__global__ void gate_fused(const float* __restrict__ xa,
                           const float* __restrict__ w_gate,
                           float* __restrict__ gprob) {
  int n = blockIdx.x * blockDim.x + threadIdx.x;
  if (n >= NTOK) return;
  const float* xr = xa + (size_t)n * D_;
  float l[E_] = {0.f, 0.f, 0.f, 0.f, 0.f, 0.f, 0.f, 0.f};
  for (int d = 0; d < D_; ++d) {
    const float xv = xr[d];
    const float* wg = w_gate + (size_t)d * E_;
    #pragma unroll
    for (int e = 0; e < E_; ++e) l[e] += xv * wg[e];
  }
  bool sel[E_] = {false, false, false, false, false, false, false, false};
  for (int kk = 0; kk < E_ / 2; ++kk) {
    int bi = -1; float bv = -1e38f;
    #pragma unroll
    for (int e = 0; e < E_; ++e)
      if (!sel[e] && l[e] > bv) { bv = l[e]; bi = e; }
    sel[bi] = true;
  }
  float mx = -1e38f;
  #pragma unroll
  for (int e = 0; e < E_; ++e) if (sel[e]) mx = fmaxf(mx, l[e]);
  float s = 0.f, pp[E_];
  #pragma unroll
  for (int e = 0; e < E_; ++e) {
    pp[e] = sel[e] ? __expf(l[e] - mx) : 0.f;
    s += pp[e];
  }
  float inv = 1.0f / s;
  #pragma unroll
  for (int e = 0; e < E_; ++e) gprob[(size_t)n * E_ + e] = pp[e] * inv;
}

// ---------------------------------------------------------------------------
extern "C" void kernel_launch(void* const* d_in, const int* in_sizes, int n_in,
                              void* d_out, int out_size, void* d_ws, size_t ws_size,
                              hipStream_t stream) {
  const float* x       = (const float*)d_in[0];
  const float* wh_bias = (const float*)d_in[1];
  const float* wh_W    = (const float*)d_in[2];
  const float* Wq      = (const float*)d_in[3];
  const float* Wk      = (const float*)d_in[4];
  const float* Wv      = (const float*)d_in[5];
  const float* proj_W  = (const float*)d_in[6];
  const float* proj_b  = (const float*)d_in[7];
  const float* exp_W1  = (const float*)d_in[8];
  const float* exp_b1  = (const float*)d_in[9];
  const float* exp_W2  = (const float*)d_in[10];
  const float* exp_b2  = (const float*)d_in[11];
  const float* w_gate  = (const float*)d_in[12];
  (void)in_sizes; (void)n_in; (void)out_size;

  char* ws = (char*)d_ws;
  size_t off = 0;
  auto alloc = [&](size_t bytes) {
    void* p = ws + off; off = (off + bytes + 255) & ~(size_t)255; return p;
  };
  typedef unsigned short us;
  float* bp    = (float*)alloc(300 * 4);
  us* whp      = (us*)alloc((size_t)2 * 300 * 768 * 2);          // 2-plane, Kp=768
  us* qkvp     = (us*)alloc((size_t)2 * 192 * 320 * 2);          // 2-plane, Kp=320
  us* projp    = (us*)alloc((size_t)3 * 300 * 64 * 2);           // 3-plane, Kp=64
  us* w1p      = (us*)alloc((size_t)2 * 4800 * 320 * 2);         // 2-plane, Kp=320
  us* w2p      = (us*)alloc(((size_t)2 * 2400 * 608 + 64 * 608) * 2);  // 2-plane +guard
  float* gprob = (float*)alloc((size_t)NTOK * E_ * 4);
  us* xwreg    = (us*)alloc((size_t)2 * NTOK * 320 * 2);   // xw 2-plane / xa fp32 / h (fb)
  float* qkvb  = (float*)alloc((size_t)NTOK * 192 * 4);    // qkv+att; esum (fallback)
  us* xap      = (us*)alloc((size_t)2 * NTOK * 320 * 2);   // xa 2-plane
  // base total ~77 MB. gsum always lives in d_out.

  float* xa = (float*)xwreg;         // [NTOK][300] fp32; dead after gating

  // expert region: dedicated hpl+esum (70MB) if it fits (r12-proven), else
  // the r11-proven fallback (CH=9600, hpl=xwreg, esum=qkvb).
  const size_t hplBytes  = (size_t)2 * NTOK * 608 * 2;   // 46.7 MB
  const size_t esumBytes = (size_t)NTOK * 300 * 4;       // 23.0 MB
  int CHe;
  us* hpl;
  float* esum;
  if (off + hplBytes + esumBytes <= ws_size) {
    hpl  = (us*)alloc(hplBytes);
    esum = (float*)alloc(esumBytes);
    CHe  = NTOK;                     // 1 chunk, grid fills CUs
  } else {
    hpl  = xwreg;                    // 23.3MB <= 24.58MB
    esum = qkvb;                     // 11.5MB <= 14.75MB
    CHe  = 9600;
  }

  // --- weight pre-split ---
  biasproj_kernel<<<2, 256, 0, stream>>>(wh_bias, wh_W, bp);
  auto SP = [&](const float* s, us* dbase, int rows, int K, int Kp, size_t pstr, int np) {
    int n = rows * Kp;
    int g = (n + 255) / 256; if (g > 4096) g = 4096;
    split_pad<<<g, 256, 0, stream>>>(s, dbase, rows, K, Kp, pstr, np);
  };
  SP(wh_W,   whp,              300,  768, 768, (size_t)300 * 768, 2);
  SP(Wq,     qkvp,             64,   300, 320, (size_t)192 * 320, 2);
  SP(Wk,     qkvp + 64 * 320,  64,   300, 320, (size_t)192 * 320, 2);
  SP(Wv,     qkvp + 128 * 320, 64,   300, 320, (size_t)192 * 320, 2);
  SP(proj_W, projp,            300,  64,  64,  (size_t)300 * 64, 3);
  SP(exp_W1, w1p,              4800, 300, 320, (size_t)4800 * 320, 2);
  SP(exp_W2, w2p,              2400, 600, 608, (size_t)2400 * 608, 2);

  // --- K1: whiten (2-plane both sides, split2 AFP staging) -> xw 2-plane ---
  {
    dim3 g(5, NTOK / 128);
    mfma_gen<1, 5, 2, 4, 2, 2, 1><<<g, 256, 0, stream>>>(
        x, 0, DIN_, whp, (size_t)300 * 768, bp, nullptr,
        xwreg, (size_t)NTOK * 320, 320, nullptr, nullptr, nullptr,
        NTOK, D_, DIN_);
  }
  // --- K2: fused QKV [NTOK][192], 2-plane both sides ---
  {
    dim3 g(3, NTOK / 128);
    mfma_gen<0, 0, 2, 4, 2, 2, 1><<<g, 256, 0, stream>>>(
        xwreg, (size_t)NTOK * 320, 0, qkvp, (size_t)192 * 320, nullptr, qkvb,
        nullptr, 0, 0, nullptr, nullptr, nullptr,
        NTOK, 192, D_);
  }
  // --- K3: attention (KV-shared blocks; att in-place over q part) ---
  attn_kernel<<<B_ * (T_ / TW), 64 * TW, 0, stream>>>(qkvb, qkvb);

  // --- K4: proj (3-plane math, AFP staging) -> xa fp32 + xa 2-plane ---
  {
    dim3 g(5, NTOK / 128);
    mfma_gen<1, 6, 2, 4, 3, 2, 1><<<g, 256, 0, stream>>>(
        qkvb, 0, 192, projp, (size_t)300 * 64, proj_b, xa,
        xap, (size_t)NTOK * 320, 320, nullptr, nullptr, nullptr,
        NTOK, D_, 64);
  }
  // --- K5: fused gating (logits + top-4 softmax) ---
  gate_fused<<<(NTOK + 255) / 256, 256, 0, stream>>>(xa, w_gate, gprob);

  // --- K6: experts (2-plane, r14 shapes + T1 swizzle); gsum in d_out ---
  for (int c = 0; c < NTOK / CHe; ++c) {
    const int tok0 = c * CHe;
    float* gsum = (float*)d_out + (size_t)tok0 * D_;
    dim3 g1(5, CHe / 128);   // G1: 128x128 tiles (JN=4), 32KB LDS
    dim3 g2(5, CHe / 128);   // G2: 128x64 tiles (JN=2), 24KB LDS
    for (int e = 0; e < E_; ++e) {
      const us* w1e = w1p + (size_t)e * 600 * 320;
      const us* w2e = w2p + (size_t)e * 300 * 608;
      const float* bb1 = exp_b1 + (size_t)e * 600;
      const float* bb2 = exp_b2 + (size_t)e * D_;
      const float* gate = gprob + (size_t)tok0 * E_ + e;
      // G1: h_2planes = split2(relu(xa @ W1^T + b1)), pads zeroed
      mfma_gen<0, 1, 4, 4, 2, 2, 1><<<g1, 256, 0, stream>>>(
          xap + (size_t)tok0 * 320, (size_t)NTOK * 320, 0,
          w1e, (size_t)4800 * 320, bb1, nullptr,
          hpl, (size_t)CHe * 608, 608, nullptr, nullptr, nullptr,
          CHe, 600, D_);
      // G2: eo = h @ W2^T + b2 folded into gsum/esum (final e writes out)
      if (e == 0)
        mfma_gen<0, 2, 2, 4, 2, 2, 1><<<g2, 256, 0, stream>>>(
            hpl, (size_t)CHe * 608, 0, w2e, (size_t)2400 * 608, bb2, nullptr,
            nullptr, 0, 0, gsum, esum, gate, CHe, D_, 600);
      else if (e < E_ - 1)
        mfma_gen<0, 3, 2, 4, 2, 2, 1><<<g2, 256, 0, stream>>>(
            hpl, (size_t)CHe * 608, 0, w2e, (size_t)2400 * 608, bb2, nullptr,
            nullptr, 0, 0, gsum, esum, gate, CHe, D_, 600);
      else
        mfma_gen<0, 4, 2, 4, 2, 2, 1><<<g2, 256, 0, stream>>>(
            hpl, (size_t)CHe * 608, 0, w2e, (size_t)2400 * 608, bb2,
            (float*)d_out + (size_t)tok0 * D_,
            nullptr, 0, 0, gsum, esum, gate, CHe, D_, 600);
    }
  }
}

// Round 20
// 901.310 us; speedup vs baseline: 1.0979x; 1.0001x over previous
//
#include <hip/hip_runtime.h>
#include <cstdint>
#include <cstddef>

#define B_   64
#define T_   300
#define DIN_ 768
#define D_   300
#define E_   8
#define NTOK (B_*T_)   // 19200
#define TW   6         // t's per attention block (6 waves)
#define SC   32        // KV staging chunk rows
#define KVP  76        // kv row stride (76%32=12 -> 2-way banks on QK reads)

typedef __attribute__((ext_vector_type(8))) short bf8_t;           // 8 bf16 (4 VGPR)
typedef __attribute__((ext_vector_type(4))) float f4_t;            // 4 fp32 acc

__device__ __forceinline__ unsigned short f2bf(float v) {
  union { float f; unsigned u; } a; a.f = v;
  unsigned r = a.u + 0x7fff + ((a.u >> 16) & 1);   // RNE
  return (unsigned short)(r >> 16);
}
__device__ __forceinline__ float bf2f(unsigned short s) {
  union { float f; unsigned u; } a; a.u = ((unsigned)s) << 16; return a.f;
}
// v ~= p0 + p1 + p2 (24 mantissa bits)
__device__ __forceinline__ void split3(float v, unsigned short& p0,
                                       unsigned short& p1, unsigned short& p2) {
  p0 = f2bf(v);
  float r1 = v - bf2f(p0);
  p1 = f2bf(r1);
  float r2 = r1 - bf2f(p1);
  p2 = f2bf(r2);
}
// v ~= p0 + p1 (17 mantissa bits)
__device__ __forceinline__ void split2(float v, unsigned short& p0,
                                       unsigned short& p1) {
  p0 = f2bf(v);
  p1 = f2bf(v - bf2f(p0));
}

// direct global->LDS 16B DMA (width=16, m97/m151 pattern)
__device__ __forceinline__ void gld16(const unsigned short* g, unsigned short* l) {
  __builtin_amdgcn_global_load_lds(
      (const __attribute__((address_space(1))) unsigned int*)g,
      (__attribute__((address_space(3))) unsigned int*)l, 16, 0, 0);
}

// ---------------------------------------------------------------------------
__global__ void biasproj_kernel(const float* __restrict__ wh_bias,
                                const float* __restrict__ wh_W,
                                float* __restrict__ bp) {
  int o = blockIdx.x * blockDim.x + threadIdx.x;
  if (o >= D_) return;
  float acc = 0.f;
  const float* row = wh_W + (size_t)o * DIN_;
  for (int d = 0; d < DIN_; ++d) acc += wh_bias[d] * row[d];
  bp[o] = -acc;
}

// ---------------------------------------------------------------------------
// split fp32 [rows][K] -> np bf16 planes [rows][Kp], zero-padded cols
// ---------------------------------------------------------------------------
__global__ void split_pad(const float* __restrict__ src, unsigned short* __restrict__ dst,
                          int rows, int K, int Kp, size_t planeStride, int np) {
  int n = rows * Kp;
  for (int i = blockIdx.x * blockDim.x + threadIdx.x; i < n; i += gridDim.x * blockDim.x) {
    int r = i / Kp, c = i % Kp;
    unsigned short p0 = 0, p1 = 0, p2 = 0;
    if (c < K) split3(src[(size_t)r * K + c], p0, p1, p2);
    dst[i] = p0;
    dst[planeStride + i] = p1;
    if (np == 3) dst[2 * planeStride + i] = p2;
  }
}

// ---------------------------------------------------------------------------
// MFMA GEMM, fp32 emulated via NP bf16 planes (NP=3: 6 products; NP=2: 3).
// (r15-proven body: frag-reads -> barrier -> next-stage issue ∥ MFMA -> barrier)
// Staging: B (and A when AFP=0) via global_load_lds width-16 into LINEAR LDS
// [row][32 shorts], chunk-XOR swizzle c_phys = c_log ^ ((row>>1)&3) applied
// on SOURCE address and FRAG-READ address (both-sides rule).
// SWZ=1: bijective XCD-aware block remap (T1, m204 form).
// AFP=1: A fp32 split-on-stage via ds_write (split3 for NP=3, split2 for NP=2).
// EPI: 0 = C = acc (+bias)                    [fp32 out]
//      1 = planes(relu(acc+bias)) -> Po       [G1 -> h planes]
//      2 = gsum = g*eo, esum = eo             (eo = acc+bias)
//      3 = gsum += g*eo, esum += eo
//      4 = C = (gsum+g*eo)*(esum+eo)
//      5 = planes(acc+bias) -> Po             [whiten -> xw planes]
//      6 = C = acc+bias AND planes -> Po      [proj -> xa + xa planes]
// Plane epilogues ZERO pads for N <= col < ldPo (NaN*0=NaN downstream else).
// ---------------------------------------------------------------------------
template<int AFP, int EPI, int JN, int WM, int NP, int NPO, int SWZ>
__global__ __launch_bounds__(WM * 64) void mfma_gen(
    const void* __restrict__ Av, size_t aPStride, int ldA,
    const unsigned short* __restrict__ Bg, size_t bPStride,
    const float* __restrict__ bias, float* __restrict__ C,
    unsigned short* __restrict__ Po, size_t poStride, int ldPo,
    float* __restrict__ gsum, float* __restrict__ esum,
    const float* __restrict__ gate,
    int M, int N, int K) {
  constexpr int TILE_M = WM * 32;
  constexpr int BROWS  = JN * 32;
  constexpr int APB    = TILE_M * 64;        // bytes per A plane in LDS
  constexpr int BPB    = BROWS * 64;
  constexpr int AINSTS = NP * APB / 1024;    // gload_lds instrs for A
  constexpr int BINSTS = NP * BPB / 1024;
  __shared__ unsigned short Ap[NP][TILE_M * 32];
  __shared__ unsigned short Bp[NP][BROWS * 32];
  const int tid = threadIdx.x;
  // block-id -> tile mapping (optionally XCD-swizzled, bijective for any nwg)
  int bxv = blockIdx.x, byv = blockIdx.y;
  if constexpr (SWZ) {
    const int nx  = gridDim.x;
    const int nwg = nx * gridDim.y;
    const int id  = byv * nx + bxv;
    const int xcd = id & 7, idx = id >> 3;
    const int q = nwg >> 3, r = nwg & 7;
    const int nid = (xcd < r) ? (xcd * (q + 1) + idx)
                              : (r * (q + 1) + (xcd - r) * q + idx);
    bxv = nid % nx;
    byv = nid / nx;
  }
  const int bm = byv * TILE_M, bn = bxv * BROWS;
  const int widx = tid >> 6;
  const int wr = (widx >> 1) * 64;           // 0 when WM=2
  const int wc = (widx & 1) * (JN * 16);
  const int lane = tid & 63;
  const int lr = lane & 15;
  const int kg = lane >> 4;
  const int sw = (lr >> 1) & 3;              // read-side chunk swizzle
  const int Kp = (K + 31) & ~31;
  // AFP staging map
  const int arow = tid >> 1, ahalf = (tid & 1) * 16;
  const int asw = (arow >> 1) & 3;

  auto stageB = [&](int k0) {
    for (int q = widx; q < BINSTS; q += WM) {
      const int f   = q * 1024 + lane * 16;
      const int pp  = f / BPB;
      const int rem = f % BPB;
      const int row = rem >> 6;
      const int cl  = ((rem >> 4) & 3) ^ ((row >> 1) & 3);
      int brow = bn + row; if (brow >= N) brow = N - 1;
      gld16(Bg + (size_t)pp * bPStride + (size_t)brow * Kp + k0 + cl * 8,
            (unsigned short*)Bp + q * 512);
    }
  };
  auto stageA = [&](int k0) {
    if constexpr (AFP) {
      const float* Arow = (const float*)Av + (size_t)(bm + arow) * ldA + k0 + ahalf;
      #pragma unroll
      for (int u = 0; u < 4; ++u) {
        float4 qv = *(const float4*)&Arow[u * 4];
        float vv[4] = {qv.x, qv.y, qv.z, qv.w};
        unsigned short s0[4], s1[4], s2[4];
        #pragma unroll
        for (int w = 0; w < 4; ++w) {
          if constexpr (NP == 3) split3(vv[w], s0[w], s1[w], s2[w]);
          else                   split2(vv[w], s0[w], s1[w]);
        }
        const int k  = ahalf + u * 4;
        const int so = arow * 32 + (((k >> 3) ^ asw) << 3) + (k & 7);
        *(unsigned*)&Ap[0][so]     = (unsigned)s0[0] | ((unsigned)s0[1] << 16);
        *(unsigned*)&Ap[0][so + 2] = (unsigned)s0[2] | ((unsigned)s0[3] << 16);
        *(unsigned*)&Ap[1][so]     = (unsigned)s1[0] | ((unsigned)s1[1] << 16);
        *(unsigned*)&Ap[1][so + 2] = (unsigned)s1[2] | ((unsigned)s1[3] << 16);
        if constexpr (NP == 3) {
          *(unsigned*)&Ap[2][so]     = (unsigned)s2[0] | ((unsigned)s2[1] << 16);
          *(unsigned*)&Ap[2][so + 2] = (unsigned)s2[2] | ((unsigned)s2[3] << 16);
        }
      }
    } else {
      for (int q = widx; q < AINSTS; q += WM) {
        const int f   = q * 1024 + lane * 16;
        const int pp  = f / APB;
        const int rem = f % APB;
        const int row = rem >> 6;
        const int cl  = ((rem >> 4) & 3) ^ ((row >> 1) & 3);
        gld16((const unsigned short*)Av + (size_t)pp * aPStride +
                  (size_t)(bm + row) * Kp + k0 + cl * 8,
              (unsigned short*)Ap + q * 512);
      }
    }
  };

  f4_t acc[4][JN];
  #pragma unroll
  for (int i = 0; i < 4; ++i)
    #pragma unroll
    for (int j = 0; j < JN; ++j) acc[i][j] = (f4_t){0.f, 0.f, 0.f, 0.f};

  stageB(0); stageA(0);
  __syncthreads();
  for (int k0 = 0; k0 < Kp; k0 += 32) {
    // ---- frag reads (swizzled) ----
    bf8_t a[4][NP], b[JN][NP];
    #pragma unroll
    for (int i = 0; i < 4; ++i)
      #pragma unroll
      for (int p = 0; p < NP; ++p)
        a[i][p] = *(const bf8_t*)&Ap[p][(wr + i * 16 + lr) * 32 + ((kg ^ sw) << 3)];
    #pragma unroll
    for (int j = 0; j < JN; ++j)
      #pragma unroll
      for (int p = 0; p < NP; ++p)
        b[j][p] = *(const bf8_t*)&Bp[p][(wc + j * 16 + lr) * 32 + ((kg ^ sw) << 3)];
    __syncthreads();   // all waves done reading -> LDS reusable
    if (k0 + 32 < Kp) { stageB(k0 + 32); stageA(k0 + 32); }   // fly under MFMA
    #pragma unroll
    for (int i = 0; i < 4; ++i)
      #pragma unroll
      for (int j = 0; j < JN; ++j) {
        f4_t c = acc[i][j];
        if constexpr (NP == 3) {
          c = __builtin_amdgcn_mfma_f32_16x16x32_bf16(a[i][2], b[j][0], c, 0, 0, 0);
          c = __builtin_amdgcn_mfma_f32_16x16x32_bf16(a[i][1], b[j][1], c, 0, 0, 0);
          c = __builtin_amdgcn_mfma_f32_16x16x32_bf16(a[i][0], b[j][2], c, 0, 0, 0);
          c = __builtin_amdgcn_mfma_f32_16x16x32_bf16(a[i][1], b[j][0], c, 0, 0, 0);
          c = __builtin_amdgcn_mfma_f32_16x16x32_bf16(a[i][0], b[j][1], c, 0, 0, 0);
          c = __builtin_amdgcn_mfma_f32_16x16x32_bf16(a[i][0], b[j][0], c, 0, 0, 0);
        } else {
          c = __builtin_amdgcn_mfma_f32_16x16x32_bf16(a[i][1], b[j][0], c, 0, 0, 0);
          c = __builtin_amdgcn_mfma_f32_16x16x32_bf16(a[i][0], b[j][1], c, 0, 0, 0);
          c = __builtin_amdgcn_mfma_f32_16x16x32_bf16(a[i][0], b[j][0], c, 0, 0, 0);
        }
        acc[i][j] = c;
      }
    __syncthreads();   // next stage drained (vmcnt+lgkm)
  }
  // ---- epilogue ----
  #pragma unroll
  for (int i = 0; i < 4; ++i) {
    #pragma unroll
    for (int r = 0; r < 4; ++r) {
      const int row = bm + wr + i * 16 + kg * 4 + r;
      float g = 0.f;
      if constexpr (EPI >= 2 && EPI <= 4) g = gate[(size_t)row * E_];
      #pragma unroll
      for (int j = 0; j < JN; ++j) {
        const int col = bn + wc + j * 16 + lr;
        float v = acc[i][j][r];
        if constexpr (EPI == 0) {
          if (col < N) {
            if (bias) v += bias[col];
            C[(size_t)row * N + col] = v;
          }
        } else if constexpr (EPI == 1 || EPI == 5 || EPI == 6) {
          if (col < ldPo) {
            unsigned short p0 = 0, p1 = 0, p2 = 0;
            if (col < N) {
              v += bias[col];
              if constexpr (EPI == 1) v = fmaxf(v, 0.f);
              if constexpr (EPI == 6) C[(size_t)row * N + col] = v;
              if constexpr (NPO == 3) split3(v, p0, p1, p2);
              else                    split2(v, p0, p1);
            }
            size_t o = (size_t)row * ldPo + col;
            Po[o] = p0;
            Po[poStride + o] = p1;
            if constexpr (NPO == 3) Po[2 * poStride + o] = p2;
          }
        } else {
          if (col < N) {
            float eo = v + bias[col];
            size_t idx = (size_t)row * N + col;
            if constexpr (EPI == 2) {
              gsum[idx] = g * eo;
              esum[idx] = eo;
            } else if constexpr (EPI == 3) {
              gsum[idx] += g * eo;
              esum[idx] += eo;
            } else {
              float gs = gsum[idx] + g * eo;
              float es = esum[idx] + eo;
              C[idx] = gs * es;
            }
          }
        }
      }
    }
  }
}

// ---------------------------------------------------------------------------
// Attention, KV-shared form (r18 proven: TW=6, SC=32, p[TW][4][304]).
// r20: kv row stride 68 -> 76 floats (bank period 8, 2-way = free) to kill
// the 2.9M-cycle 8-way conflict on QK-pass reads. Math order unchanged.
// ---------------------------------------------------------------------------
__global__ __launch_bounds__(64 * TW) void attn_kernel(
    const float* __restrict__ qkv, float* __restrict__ attout) {
  const int nch_blk = T_ / TW;               // 50
  const int b   = blockIdx.x / nch_blk;
  const int tch = blockIdx.x % nch_blk;
  const int w    = threadIdx.x >> 6;
  const int lane = threadIdx.x & 63;
  const int h = lane >> 4, li = lane & 15;
  const int t    = tch * TW + w;
  const int tmax = tch * TW + TW - 1;
  __shared__ float kv[SC][KVP];              // K chunk, then reused for V
  __shared__ float p[TW][4][304];            // per-(wave, head) score rows
  const float scale = rsqrtf((float)D_);
  const float* base = qkv + (size_t)b * T_ * 192;
  const float* qrow = base + (size_t)t * 192 + h * 16;
  const float4 q0 = *(const float4*)(qrow);
  const float4 q1 = *(const float4*)(qrow + 4);
  const float4 q2 = *(const float4*)(qrow + 8);
  const float4 q3 = *(const float4*)(qrow + 12);
  const int nch = tmax / SC + 1;             // chunks covering s in [0, tmax]

  // ---- pass 1: K chunks -> scores in p[w][h][*], track per-lane max ----
  float mmax = -1e30f;
  for (int c = 0; c < nch; ++c) {
    const int s0 = c * SC;
    __syncthreads();                          // prior chunk fully consumed
    for (int i = threadIdx.x; i < SC * 16; i += 64 * TW) {
      const int r = i >> 4, c4 = (i & 15) * 4;
      int sr = s0 + r; if (sr > T_ - 1) sr = T_ - 1;   // clamped rows unused
      *(float4*)&kv[r][c4] = *(const float4*)&base[(size_t)sr * 192 + 64 + c4];
    }
    __syncthreads();
    const int send = (s0 + SC - 1 < t) ? s0 + SC - 1 : t;
    for (int s = s0 + li; s <= send; s += 16) {
      const float* kr = &kv[s - s0][h * 16];
      float4 k0 = *(const float4*)(kr);
      float4 k1 = *(const float4*)(kr + 4);
      float4 k2 = *(const float4*)(kr + 8);
      float4 k3 = *(const float4*)(kr + 12);
      float acc = q0.x * k0.x + q0.y * k0.y + q0.z * k0.z + q0.w * k0.w;
      acc += q1.x * k1.x + q1.y * k1.y + q1.z * k1.z + q1.w * k1.w;
      acc += q2.x * k2.x + q2.y * k2.y + q2.z * k2.z + q2.w * k2.w;
      acc += q3.x * k3.x + q3.y * k3.y + q3.z * k3.z + q3.w * k3.w;
      acc *= scale;
      p[w][h][s] = acc;
      mmax = fmaxf(mmax, acc);
    }
  }
  // ---- softmax (own (w,h) rows; 16-lane reduction as r11) ----
  #pragma unroll
  for (int m = 8; m >= 1; m >>= 1) mmax = fmaxf(mmax, __shfl_xor(mmax, m, 16));
  float lsum = 0.f;
  for (int s = li; s <= t; s += 16) {
    float e = __expf(p[w][h][s] - mmax);
    p[w][h][s] = e;
    lsum += e;
  }
  #pragma unroll
  for (int m = 8; m >= 1; m >>= 1) lsum += __shfl_xor(lsum, m, 16);
  const float inv = 1.0f / lsum;

  // ---- pass 2: V chunks -> PV accumulate (r11 order preserved) ----
  float o0 = 0.f, o1 = 0.f, o2 = 0.f, o3 = 0.f;
  for (int c = 0; c < nch; ++c) {
    const int s0 = c * SC;
    __syncthreads();                          // K/prev-V reads done
    for (int i = threadIdx.x; i < SC * 16; i += 64 * TW) {
      const int r = i >> 4, c4 = (i & 15) * 4;
      int sr = s0 + r; if (sr > T_ - 1) sr = T_ - 1;
      *(float4*)&kv[r][c4] = *(const float4*)&base[(size_t)sr * 192 + 128 + c4];
    }
    __syncthreads();
    const int send = (s0 + SC - 1 < t) ? s0 + SC - 1 : t;
    const int col = h * 16 + li;
    int s = s0;
    for (; s + 3 <= send; s += 4) {
      float4 pw = *(const float4*)&p[w][h][s];
      o0 += pw.x * kv[s - s0][col];
      o1 += pw.y * kv[s + 1 - s0][col];
      o2 += pw.z * kv[s + 2 - s0][col];
      o3 += pw.w * kv[s + 3 - s0][col];
    }
    for (; s <= send; ++s) o0 += p[w][h][s] * kv[s - s0][col];
  }
  attout[((size_t)b * T_ + t) * 192 + lane] = ((o0 + o1) + (o2 + o3)) * inv;
}

// ---------------------------------------------------------------------------
// Fused gating: logits (same accumulation order) + top-4 sparse softmax.
// ---------------------------------------------------------------------------
__global__ void gate_fused(const float* __restrict__ xa,
                           const float* __restrict__ w_gate,
                           float* __restrict__ gprob) {
  int n = blockIdx.x * blockDim.x + threadIdx.x;
  if (n >= NTOK) return;
  const float* xr = xa + (size_t)n * D_;
  float l[E_] = {0.f, 0.f, 0.f, 0.f, 0.f, 0.f, 0.f, 0.f};
  for (int d = 0; d < D_; ++d) {
    const float xv = xr[d];
    const float* wg = w_gate + (size_t)d * E_;
    #pragma unroll
    for (int e = 0; e < E_; ++e) l[e] += xv * wg[e];
  }
  bool sel[E_] = {false, false, false, false, false, false, false, false};
  for (int kk = 0; kk < E_ / 2; ++kk) {
    int bi = -1; float bv = -1e38f;
    #pragma unroll
    for (int e = 0; e < E_; ++e)
      if (!sel[e] && l[e] > bv) { bv = l[e]; bi = e; }
    sel[bi] = true;
  }
  float mx = -1e38f;
  #pragma unroll
  for (int e = 0; e < E_; ++e) if (sel[e]) mx = fmaxf(mx, l[e]);
  float s = 0.f, pp[E_];
  #pragma unroll
  for (int e = 0; e < E_; ++e) {
    pp[e] = sel[e] ? __expf(l[e] - mx) : 0.f;
    s += pp[e];
  }
  float inv = 1.0f / s;
  #pragma unroll
  for (int e = 0; e < E_; ++e) gprob[(size_t)n * E_ + e] = pp[e] * inv;
}

// ---------------------------------------------------------------------------
extern "C" void kernel_launch(void* const* d_in, const int* in_sizes, int n_in,
                              void* d_out, int out_size, void* d_ws, size_t ws_size,
                              hipStream_t stream) {
  const float* x       = (const float*)d_in[0];
  const float* wh_bias = (const float*)d_in[1];
  const float* wh_W    = (const float*)d_in[2];
  const float* Wq      = (const float*)d_in[3];
  const float* Wk      = (const float*)d_in[4];
  const float* Wv      = (const float*)d_in[5];
  const float* proj_W  = (const float*)d_in[6];
  const float* proj_b  = (const float*)d_in[7];
  const float* exp_W1  = (const float*)d_in[8];
  const float* exp_b1  = (const float*)d_in[9];
  const float* exp_W2  = (const float*)d_in[10];
  const float* exp_b2  = (const float*)d_in[11];
  const float* w_gate  = (const float*)d_in[12];
  (void)in_sizes; (void)n_in; (void)out_size;

  char* ws = (char*)d_ws;
  size_t off = 0;
  auto alloc = [&](size_t bytes) {
    void* p = ws + off; off = (off + bytes + 255) & ~(size_t)255; return p;
  };
  typedef unsigned short us;
  float* bp    = (float*)alloc(300 * 4);
  us* whp      = (us*)alloc((size_t)2 * 300 * 768 * 2);          // 2-plane, Kp=768
  us* qkvp     = (us*)alloc((size_t)2 * 192 * 320 * 2);          // 2-plane, Kp=320
  us* projp    = (us*)alloc((size_t)2 * 300 * 64 * 2);           // 2-plane, Kp=64
  us* w1p      = (us*)alloc((size_t)2 * 4800 * 320 * 2);         // 2-plane, Kp=320
  us* w2p      = (us*)alloc(((size_t)2 * 2400 * 608 + 64 * 608) * 2);  // 2-plane +guard
  float* gprob = (float*)alloc((size_t)NTOK * E_ * 4);
  us* xwreg    = (us*)alloc((size_t)2 * NTOK * 320 * 2);   // xw 2-plane / xa fp32 / h (fb)
  float* qkvb  = (float*)alloc((size_t)NTOK * 192 * 4);    // qkv+att; esum (fallback)
  us* xap      = (us*)alloc((size_t)2 * NTOK * 320 * 2);   // xa 2-plane
  // base total ~77 MB. gsum always lives in d_out.

  float* xa = (float*)xwreg;         // [NTOK][300] fp32; dead after gating

  // expert region: dedicated hpl+esum (70MB) if it fits (r12-proven), else
  // the r11-proven fallback (CH=9600, hpl=xwreg, esum=qkvb).
  const size_t hplBytes  = (size_t)2 * NTOK * 608 * 2;   // 46.7 MB
  const size_t esumBytes = (size_t)NTOK * 300 * 4;       // 23.0 MB
  int CHe;
  us* hpl;
  float* esum;
  if (off + hplBytes + esumBytes <= ws_size) {
    hpl  = (us*)alloc(hplBytes);
    esum = (float*)alloc(esumBytes);
    CHe  = NTOK;                     // 1 chunk, grid fills CUs
  } else {
    hpl  = xwreg;                    // 23.3MB <= 24.58MB
    esum = qkvb;                     // 11.5MB <= 14.75MB
    CHe  = 9600;
  }

  // --- weight pre-split ---
  biasproj_kernel<<<2, 256, 0, stream>>>(wh_bias, wh_W, bp);
  auto SP = [&](const float* s, us* dbase, int rows, int K, int Kp, size_t pstr, int np) {
    int n = rows * Kp;
    int g = (n + 255) / 256; if (g > 4096) g = 4096;
    split_pad<<<g, 256, 0, stream>>>(s, dbase, rows, K, Kp, pstr, np);
  };
  SP(wh_W,   whp,              300,  768, 768, (size_t)300 * 768, 2);
  SP(Wq,     qkvp,             64,   300, 320, (size_t)192 * 320, 2);
  SP(Wk,     qkvp + 64 * 320,  64,   300, 320, (size_t)192 * 320, 2);
  SP(Wv,     qkvp + 128 * 320, 64,   300, 320, (size_t)192 * 320, 2);
  SP(proj_W, projp,            300,  64,  64,  (size_t)300 * 64, 2);
  SP(exp_W1, w1p,              4800, 300, 320, (size_t)4800 * 320, 2);
  SP(exp_W2, w2p,              2400, 600, 608, (size_t)2400 * 608, 2);

  // --- K1: whiten (2-plane both sides, split2 AFP staging) -> xw 2-plane ---
  {
    dim3 g(5, NTOK / 128);
    mfma_gen<1, 5, 2, 4, 2, 2, 1><<<g, 256, 0, stream>>>(
        x, 0, DIN_, whp, (size_t)300 * 768, bp, nullptr,
        xwreg, (size_t)NTOK * 320, 320, nullptr, nullptr, nullptr,
        NTOK, D_, DIN_);
  }
  // --- K2: fused QKV [NTOK][192], 2-plane both sides ---
  {
    dim3 g(3, NTOK / 128);
    mfma_gen<0, 0, 2, 4, 2, 2, 1><<<g, 256, 0, stream>>>(
        xwreg, (size_t)NTOK * 320, 0, qkvp, (size_t)192 * 320, nullptr, qkvb,
        nullptr, 0, 0, nullptr, nullptr, nullptr,
        NTOK, 192, D_);
  }
  // --- K3: attention (KV-shared blocks; att in-place over q part) ---
  attn_kernel<<<B_ * (T_ / TW), 64 * TW, 0, stream>>>(qkvb, qkvb);

  // --- K4: proj (2-plane both sides, split2 AFP staging) -> xa + xa planes ---
  {
    dim3 g(5, NTOK / 128);
    mfma_gen<1, 6, 2, 4, 2, 2, 1><<<g, 256, 0, stream>>>(
        qkvb, 0, 192, projp, (size_t)300 * 64, proj_b, xa,
        xap, (size_t)NTOK * 320, 320, nullptr, nullptr, nullptr,
        NTOK, D_, 64);
  }
  // --- K5: fused gating (logits + top-4 softmax) ---
  gate_fused<<<(NTOK + 255) / 256, 256, 0, stream>>>(xa, w_gate, gprob);

  // --- K6: experts (2-plane, r14 shapes + T1 swizzle); gsum in d_out ---
  for (int c = 0; c < NTOK / CHe; ++c) {
    const int tok0 = c * CHe;
    float* gsum = (float*)d_out + (size_t)tok0 * D_;
    dim3 g1(5, CHe / 128);   // G1: 128x128 tiles (JN=4), 32KB LDS
    dim3 g2(5, CHe / 128);   // G2: 128x64 tiles (JN=2), 24KB LDS
    for (int e = 0; e < E_; ++e) {
      const us* w1e = w1p + (size_t)e * 600 * 320;
      const us* w2e = w2p + (size_t)e * 300 * 608;
      const float* bb1 = exp_b1 + (size_t)e * 600;
      const float* bb2 = exp_b2 + (size_t)e * D_;
      const float* gate = gprob + (size_t)tok0 * E_ + e;
      // G1: h_2planes = split2(relu(xa @ W1^T + b1)), pads zeroed
      mfma_gen<0, 1, 4, 4, 2, 2, 1><<<g1, 256, 0, stream>>>(
          xap + (size_t)tok0 * 320, (size_t)NTOK * 320, 0,
          w1e, (size_t)4800 * 320, bb1, nullptr,
          hpl, (size_t)CHe * 608, 608, nullptr, nullptr, nullptr,
          CHe, 600, D_);
      // G2: eo = h @ W2^T + b2 folded into gsum/esum (final e writes out)
      if (e == 0)
        mfma_gen<0, 2, 2, 4, 2, 2, 1><<<g2, 256, 0, stream>>>(
            hpl, (size_t)CHe * 608, 0, w2e, (size_t)2400 * 608, bb2, nullptr,
            nullptr, 0, 0, gsum, esum, gate, CHe, D_, 600);
      else if (e < E_ - 1)
        mfma_gen<0, 3, 2, 4, 2, 2, 1><<<g2, 256, 0, stream>>>(
            hpl, (size_t)CHe * 608, 0, w2e, (size_t)2400 * 608, bb2, nullptr,
            nullptr, 0, 0, gsum, esum, gate, CHe, D_, 600);
      else
        mfma_gen<0, 4, 2, 4, 2, 2, 1><<<g2, 256, 0, stream>>>(
            hpl, (size_t)CHe * 608, 0, w2e, (size_t)2400 * 608, bb2,
            (float*)d_out + (size_t)tok0 * D_,
            nullptr, 0, 0, gsum, esum, gate, CHe, D_, 600);
    }
  }
}